// Round 18
// baseline (325.558 us; speedup 1.0000x reference)
//
#include <hip/hip_runtime.h>
#include <hip/hip_bf16.h>
#include <math.h>

#define HF 129
#define WF 129
#define BDIM 2
#define TOK (BDIM*HF*WF)   /* 33282 */
#define DMOD 128
#define VTP 104            /* Vt / P pitch in bf16 elems (208 B, 16B-aligned, bank-spread) */

typedef __attribute__((ext_vector_type(8))) short short8;
typedef __attribute__((ext_vector_type(8))) unsigned short ushort8;
typedef __attribute__((ext_vector_type(4))) float f32x4;

__device__ __forceinline__ float leaky(float v){ return v > 0.f ? v : 0.01f*v; }
__device__ __forceinline__ float bf2f(unsigned short u){ return __uint_as_float(((unsigned int)u) << 16); }
__device__ __forceinline__ unsigned int f2bf(float f){
    unsigned int u = __float_as_uint(f);
    return (u + 0x7fff + ((u >> 16) & 1)) >> 16;
}

// ---------------- one-shot weight prep ----------------
#define NQ 147456
#define NPJ 49152
#define N1 196608
#define N2 196608
#define NPAT 8192
#define NDEP 8192
__global__ __launch_bounds__(256) void prep_weights(
    const float* __restrict__ qkv_w, const float* __restrict__ proj_w,
    const float* __restrict__ fc1_w, const float* __restrict__ fc2_w,
    const float* __restrict__ patch_w, const float* __restrict__ dep_w,
    __hip_bfloat16* __restrict__ wq, __hip_bfloat16* __restrict__ wp,
    __hip_bfloat16* __restrict__ w1, __hip_bfloat16* __restrict__ w2,
    __hip_bfloat16* __restrict__ wpat, __hip_bfloat16* __restrict__ wdep,
    float* __restrict__ zero64)
{
    int off = blockIdx.x*256 + threadIdx.x;
    if (off < NQ) { wq[off] = __float2bfloat16(qkv_w[off]); return; } off -= NQ;
    if (off < NPJ){ wp[off] = __float2bfloat16(proj_w[off]); return; } off -= NPJ;
    if (off < N1) { w1[off] = __float2bfloat16(fc1_w[off]); return; } off -= N1;
    if (off < N2) { w2[off] = __float2bfloat16(fc2_w[off]); return; } off -= N2;
    if (off < NPAT){ int r = off>>6, e = off&63;
        wpat[off] = __float2bfloat16(e < 48 ? patch_w[r*48 + e] : 0.f); return; } off -= NPAT;
    if (off < NDEP){ int e = off>>7, d = off&127;
        wdep[off] = __float2bfloat16(e < 48 ? dep_w[d*48 + e] : 0.f); return; } off -= NDEP;
    if (off < 64) zero64[off] = 0.f;
}

// ---------------- im2col for patchify ----------------
__global__ __launch_bounds__(256) void im2col_kernel(
    const float* __restrict__ x, const float* __restrict__ pos_w, const float* __restrict__ pos_b,
    __hip_bfloat16* __restrict__ G)
{
    __shared__ float xs[12][260];
    int blk = blockIdx.x;           // b*HF + oh
    int b = blk / HF, oh = blk - b*HF;
    int tid = threadIdx.x;
    #pragma unroll
    for (int it = 0; it < 3; ++it) {
        int p = it*4 + (tid >> 6);
        int c = p >> 2, r = p & 3;
        int h = (oh*2 + r - 2 + 256) & 255;
        int w4 = (tid & 63) * 4;
        float4 xv  = *(const float4*)(x     + ((size_t)(b*3 + c)*256 + h)*256 + w4);
        float4 pwv = *(const float4*)(pos_w + ((size_t)c*256 + h)*256 + w4);
        float4 pbv = *(const float4*)(pos_b + ((size_t)c*256 + h)*256 + w4);
        float4 o; o.x = xv.x*pwv.x + pbv.x; o.y = xv.y*pwv.y + pbv.y;
        o.z = xv.z*pwv.z + pbv.z; o.w = xv.w*pwv.w + pbv.w;
        *(float4*)&xs[p][w4] = o;
    }
    __syncthreads();
    int e = tid & 63, og = tid >> 6;
    int c = e >> 4, k = e & 15, kh = k >> 2, kw = k & 3;
    int p = c*4 + kh;
    unsigned short* Grow = (unsigned short*)G + (size_t)blk*WF*64;
    for (int ow = og; ow < WF; ow += 4) {
        unsigned short v = 0;
        if (e < 48) {
            int col = (ow*2 + kw - 2 + 256) & 255;
            v = (unsigned short)f2bf(xs[p][col]);
        }
        Grow[ow*64 + e] = v;
    }
}

// ---------------- gemmF: BM=64, BN=128, BK=64-chunk MFMA GEMM with optional epilogue LN ----------------
// Residual stream Cf is bf16 (LN stats still computed from f32 register accumulators).
template<int ACT, int RES, int OUTF, int LNE>
__global__ __launch_bounds__(256) void gemmF_kernel(
    const __hip_bfloat16* __restrict__ A, const __hip_bfloat16* __restrict__ W,
    const float* __restrict__ bias, const float* __restrict__ lng, const float* __restrict__ lnb,
    __hip_bfloat16* __restrict__ Cbf, __hip_bfloat16* __restrict__ Cf,
    __hip_bfloat16* __restrict__ yl, int M, int N, int K)
{
    __shared__ __align__(16) char As[64*128];
    __shared__ __align__(16) char Ws[128*128];
    __shared__ float2 lnred[64][2];
    int tid = threadIdx.x;
    int bm = blockIdx.x*64, bn = blockIdx.y*128;
    int lane = tid & 63, wid = tid >> 6;
    int wr = (wid >> 1)*32, wc = (wid & 1)*64;
    int lrow = lane & 15, lq = lane >> 4;
    int srow = tid >> 3, scg = tid & 7;
    int swz = (lrow & 7) << 4;
    int awo0 = ((srow     )*128 + scg*16) ^ ((srow&7)<<4);
    int awo1 = ((srow + 32)*128 + scg*16) ^ ((srow&7)<<4);

    bool v0 = (bm + srow) < M, v1 = (bm + srow + 32) < M;
    const __hip_bfloat16* a0p = A + (size_t)(bm + srow)*K + scg*8;
    const __hip_bfloat16* a1p = A + (size_t)(bm + srow + 32)*K + scg*8;
    const __hip_bfloat16* wp0 = W + (size_t)(bn + srow)*K + scg*8;

    f32x4 acc[2][4] = {};
    for (int k0 = 0; k0 < K; k0 += 64) {
        int4 va0 = {}, va1 = {};
        if (v0) va0 = *(const int4*)(a0p + k0);
        if (v1) va1 = *(const int4*)(a1p + k0);
        int4 vw0 = *(const int4*)(wp0 + k0);
        int4 vw1 = *(const int4*)(wp0 + (size_t)32*K + k0);
        int4 vw2 = *(const int4*)(wp0 + (size_t)64*K + k0);
        int4 vw3 = *(const int4*)(wp0 + (size_t)96*K + k0);
        __syncthreads();
        *(int4*)(As + awo0) = va0;
        *(int4*)(As + awo1) = va1;
        *(int4*)(Ws + awo0) = vw0;
        *(int4*)(Ws + awo1) = vw1;
        *(int4*)(Ws + (((srow+64)*128 + scg*16) ^ ((srow&7)<<4))) = vw2;
        *(int4*)(Ws + (((srow+96)*128 + scg*16) ^ ((srow&7)<<4))) = vw3;
        __syncthreads();
        #pragma unroll
        for (int ks = 0; ks < 2; ++ks) {
            int kb = ks*64;
            short8 af[2], bf[4];
            #pragma unroll
            for (int mi = 0; mi < 2; ++mi)
                af[mi] = *(const short8*)(As + (((wr + mi*16 + lrow)*128 + kb + lq*16) ^ swz));
            #pragma unroll
            for (int ni = 0; ni < 4; ++ni)
                bf[ni] = *(const short8*)(Ws + (((wc + ni*16 + lrow)*128 + kb + lq*16) ^ swz));
            #pragma unroll
            for (int mi = 0; mi < 2; ++mi)
                #pragma unroll
                for (int ni = 0; ni < 4; ++ni)
                    acc[mi][ni] = __builtin_amdgcn_mfma_f32_16x16x32_bf16(af[mi], bf[ni], acc[mi][ni], 0, 0, 0);
        }
    }
    float bcol[4];
    #pragma unroll
    for (int ni = 0; ni < 4; ++ni) bcol[ni] = bias[bn + wc + ni*16 + lrow];
    #pragma unroll
    for (int mi = 0; mi < 2; ++mi) {
        #pragma unroll
        for (int r = 0; r < 4; ++r) {
            int row = bm + wr + mi*16 + lq*4 + r;
            bool vrow = row < M;
            #pragma unroll
            for (int ni = 0; ni < 4; ++ni) {
                float v = acc[mi][ni][r] + bcol[ni];
                if (ACT) v = leaky(v);
                if (RES || OUTF) {
                    int col = wc + ni*16 + lrow;
                    size_t idx = (size_t)row*128 + col;
                    if (RES) {
                        float old = vrow ? bf2f(((const unsigned short*)Cf)[idx]) : 0.f;
                        v += old;
                    }
                    if (vrow) ((unsigned short*)Cf)[idx] = (unsigned short)f2bf(v);
                } else {
                    int col = bn + wc + ni*16 + lrow;
                    if (vrow) Cbf[(size_t)row*N + col] = __float2bfloat16(v);
                }
                acc[mi][ni][r] = v;
            }
        }
    }
    if (LNE) {
        float sa[8], ssa[8];
        #pragma unroll
        for (int mi = 0; mi < 2; ++mi)
            #pragma unroll
            for (int r = 0; r < 4; ++r) {
                float s = 0.f, ss = 0.f;
                #pragma unroll
                for (int ni = 0; ni < 4; ++ni) { float v = acc[mi][ni][r]; s += v; ss += v*v; }
                sa[mi*4+r] = s; ssa[mi*4+r] = ss;
            }
        #pragma unroll
        for (int m = 1; m < 16; m <<= 1) {
            #pragma unroll
            for (int i = 0; i < 8; ++i) { sa[i] += __shfl_xor(sa[i], m); ssa[i] += __shfl_xor(ssa[i], m); }
        }
        if (lrow == 0) {
            #pragma unroll
            for (int i = 0; i < 8; ++i)
                lnred[wr + (i>>2)*16 + lq*4 + (i&3)][wc>>6] = make_float2(sa[i], ssa[i]);
        }
        __syncthreads();
        float gcol[4], bbcol[4];
        #pragma unroll
        for (int ni = 0; ni < 4; ++ni) {
            gcol[ni] = lng[wc + ni*16 + lrow];
            bbcol[ni] = lnb[wc + ni*16 + lrow];
        }
        #pragma unroll
        for (int mi = 0; mi < 2; ++mi) {
            #pragma unroll
            for (int r = 0; r < 4; ++r) {
                int rl = wr + mi*16 + lq*4 + r;
                int row = bm + rl;
                if (row >= M) continue;
                float2 h0 = lnred[rl][0], h1 = lnred[rl][1];
                float mean = (h0.x + h1.x) * (1.f/128.f);
                float var = (h0.y + h1.y) * (1.f/128.f) - mean*mean;
                float inv = rsqrtf(var + 1e-5f);
                #pragma unroll
                for (int ni = 0; ni < 4; ++ni) {
                    int col = wc + ni*16 + lrow;
                    float yv = (acc[mi][ni][r] - mean)*inv*gcol[ni] + bbcol[ni];
                    yl[(size_t)row*128 + col] = __float2bfloat16(yv);
                }
            }
        }
    }
}

// ---------------- MFMA neighborhood attention, phase-split K/V (3 blocks/CU) ----------------
__global__ __launch_bounds__(256) void attn_mfma_kernel(
    const __hip_bfloat16* __restrict__ qkv, const float* __restrict__ rpb,
    __hip_bfloat16* __restrict__ o)
{
    __shared__ __align__(16) char KV[26624];           // K (phase A) -> Vt (phase B)
    __shared__ __align__(16) char Pl[4][32*VTP*2];     // per-wave P; base doubles as rpbl in phase A
    float* rpbl = (float*)Pl;
    int blk = blockIdx.x;           // b*(17*33) + tyi*33 + txi
    int b = blk / (17*33);
    int rem = blk - b*(17*33);
    int tyi = rem / 33, txi = rem - tyi*33;
    int y0 = tyi*8, x0 = txi*4;
    int tid = threadIdx.x;
    int lane = tid & 63, wid = tid >> 6;
    int lrow = lane & 15, lq = lane >> 4;

    for (int u = tid; u < 648; u += 256) rpbl[u] = rpb[u];

    // ---- phase A: stage K (c-fast coalesced, swizzled rows) ----
    #pragma unroll
    for (int it = 0; it < 6; ++it) {
        int u = tid + it*256;
        int wtok = u >> 4, c = u & 15;
        int wy = wtok >> 3, wx = wtok & 7;
        int gy = y0 + wy - 2; gy += (gy < 0) ? HF : 0; gy -= (gy >= HF) ? HF : 0;
        int gx = x0 + wx - 2; gx += (gx < 0) ? WF : 0; gx -= (gx >= WF) ? WF : 0;
        size_t tk = (size_t)(b*HF + gy)*WF + gx;
        int4 v = *(const int4*)(qkv + tk*384 + 128 + c*8);
        *(int4*)(KV + wtok*256 + ((c*16) ^ ((wtok & 7) << 4))) = v;
    }
    __syncthreads();

    // ---- phase A: QK^T + bias + exp + rowsum for BOTH heads (scores in regs) ----
    f32x4 sc[2][2][6];
    float inv[2][8];
    int wxv = lrow & 7;
    int wyb = lrow >> 3;
    #pragma unroll
    for (int hh = 0; hh < 2; ++hh) {
        int h = wid + hh*4;
        short8 aq[2];
        #pragma unroll
        for (int mi = 0; mi < 2; ++mi) {
            int q = mi*16 + lrow;
            int ty = q >> 2, tx = q & 3;
            int gy = y0 + ty, gx = x0 + tx;
            int cy = gy < HF ? gy : HF-1, cx = gx < WF ? gx : WF-1;
            size_t tk = (size_t)(b*HF + cy)*WF + cx;
            short8 v = {};
            if (lq < 2) v = *(const short8*)(qkv + tk*384 + h*16 + lq*8);
            aq[mi] = v;
        }
        #pragma unroll
        for (int ni = 0; ni < 6; ++ni) {
            int krow = ni*16 + lrow;
            short8 bk = *(const short8*)(KV + krow*256 + ((h*32 + (lq&1)*16) ^ ((krow&7)<<4)));
            f32x4 zz = {0.f,0.f,0.f,0.f};
            sc[hh][0][ni] = __builtin_amdgcn_mfma_f32_16x16x32_bf16(aq[0], bk, zz, 0, 0, 0);
            sc[hh][1][ni] = __builtin_amdgcn_mfma_f32_16x16x32_bf16(aq[1], bk, zz, 0, 0, 0);
        }
        // bias + mask (clamped f32 rpbl path; C layout: q=mi*16+lq*4+r, w=ni*16+lrow)
        #pragma unroll
        for (int mi = 0; mi < 2; ++mi) {
            int tyq = mi*4 + lq;
            #pragma unroll
            for (int ni = 0; ni < 6; ++ni) {
                int dy = ni*2 + wyb - tyq;
                bool vdy = (dy >= 0) && (dy <= 4);
                int base = (dy + 2)*9 + wxv + 2;
                int cb = base < 3 ? 3 : (base > 80 ? 80 : base);
                const float* bp = rpbl + h*81 + cb - 3;
                float b0 = bp[0], b1 = bp[1], b2 = bp[2], b3 = bp[3];
                float bias_r[4] = {b3, b2, b1, b0};   // bias[r] = rpbl[base - r]
                #pragma unroll
                for (int r = 0; r < 4; ++r) {
                    int dx = wxv - r;
                    bool ok = vdy && (dx >= 0) && (dx <= 4);
                    float s = sc[hh][mi][ni][r]*0.25f + bias_r[r];
                    sc[hh][mi][ni][r] = ok ? s : -1e30f;
                }
            }
        }
        // max-free softmax (logits O(1); masked -> exp(-1e30)=0)
        float sum[8] = {};
        #pragma unroll
        for (int mi = 0; mi < 2; ++mi)
            #pragma unroll
            for (int ni = 0; ni < 6; ++ni)
                #pragma unroll
                for (int r = 0; r < 4; ++r) {
                    float p = __expf(sc[hh][mi][ni][r]);
                    sc[hh][mi][ni][r] = p;
                    sum[mi*4 + r] += p;
                }
        #pragma unroll
        for (int msk = 1; msk < 16; msk <<= 1)
            #pragma unroll
            for (int i = 0; i < 8; ++i) sum[i] += __shfl_xor(sum[i], msk);
        #pragma unroll
        for (int i = 0; i < 8; ++i) inv[hh][i] = 1.f / sum[i];
    }
    __syncthreads();   // all K reads + rpbl reads complete

    // ---- phase B: stage Vt (transposed) into KV ----
    #pragma unroll
    for (int it = 0; it < 6; ++it) {
        int u = tid + it*256;
        int c = u / 96, wtok = u - c*96;
        int wy = wtok >> 3, wx = wtok & 7;
        int gy = y0 + wy - 2; gy += (gy < 0) ? HF : 0; gy -= (gy >= HF) ? HF : 0;
        int gx = x0 + wx - 2; gx += (gx < 0) ? WF : 0; gx -= (gx >= WF) ? WF : 0;
        size_t tk = (size_t)(b*HF + gy)*WF + gx;
        ushort8 v = *(const ushort8*)(qkv + tk*384 + 256 + c*8);
        unsigned short* dst = (unsigned short*)KV + (c*8)*VTP + wtok;
        #pragma unroll
        for (int j = 0; j < 8; ++j) dst[j*VTP] = v[j];
    }
    __syncthreads();   // Vt visible; safe to overwrite Pl (rpbl dead)

    // ---- phase B: per head P write + PV + O write ----
    char* myP = Pl[wid];
    #pragma unroll
    for (int hh = 0; hh < 2; ++hh) {
        int h = wid + hh*4;
        #pragma unroll
        for (int mi = 0; mi < 2; ++mi)
            #pragma unroll
            for (int ni = 0; ni < 6; ++ni)
                #pragma unroll
                for (int r = 0; r < 4; ++r) {
                    int q = mi*16 + lq*4 + r;
                    int w = ni*16 + lrow;
                    ((unsigned short*)myP)[q*VTP + w] =
                        (unsigned short)f2bf(sc[hh][mi][ni][r]);
                }
        f32x4 ov[2] = {};
        #pragma unroll
        for (int kk = 0; kk < 3; ++kk) {
            short8 vb = *(const short8*)(KV + (h*16 + lrow)*(VTP*2) + kk*64 + lq*16);
            #pragma unroll
            for (int mi = 0; mi < 2; ++mi) {
                short8 pa = *(const short8*)(myP + (mi*16 + lrow)*(VTP*2) + kk*64 + lq*16);
                ov[mi] = __builtin_amdgcn_mfma_f32_16x16x32_bf16(pa, vb, ov[mi], 0, 0, 0);
            }
        }
        #pragma unroll
        for (int mi = 0; mi < 2; ++mi) {
            int tyq = mi*4 + lq;
            int gy = y0 + tyq;
            #pragma unroll
            for (int r = 0; r < 4; ++r) {
                int gx = x0 + r;
                if (gy < HF && gx < WF) {
                    size_t tk = (size_t)(b*HF + gy)*WF + gx;
                    ((unsigned short*)o)[tk*128 + h*16 + lrow] =
                        (unsigned short)f2bf(ov[mi][r] * inv[hh][mi*4 + r]);
                }
            }
        }
    }
}

// ---------------- small 64x64 MFMA GEMM (depatch: bf16 f -> f32 G) ----------------
template<int ACT, int RES, int OUTF, int A32>
__global__ __launch_bounds__(256) void mgemm_kernel(
    const void* __restrict__ Av, const __hip_bfloat16* __restrict__ W,
    const float* __restrict__ bias, __hip_bfloat16* __restrict__ Cbf,
    float* __restrict__ Cres, int M, int N, int K)
{
    __shared__ __align__(16) char As[64*128];
    __shared__ __align__(16) char Ws[64*128];
    int tid = threadIdx.x;
    int bm = blockIdx.x*64, bn = blockIdx.y*64;
    int lane = tid & 63, wid = tid >> 6;
    int wm = (wid >> 1)*32, wn = (wid & 1)*32;
    int lrow = lane & 15, lq = lane >> 4;
    int srow = tid >> 3, scg = tid & 7;
    int wo0 = ((srow     )*128 + scg*16) ^ ((srow&7)<<4);
    int wo1 = ((srow + 32)*128 + scg*16) ^ ((srow&7)<<4);
    int swz = (lrow & 7) << 4;
    int baseA0 = (wm + lrow     )*128 + lq*16;
    int baseA1 = (wm + 16 + lrow)*128 + lq*16;
    int baseB0 = (wn + lrow     )*128 + lq*16;
    int baseB1 = (wn + 16 + lrow)*128 + lq*16;

    f32x4 acc[2][2] = {};
    bool v0 = (bm + srow) < M, v1 = (bm + srow + 32) < M;
    const __hip_bfloat16* a0p = (const __hip_bfloat16*)Av + (size_t)(bm + srow)*K + scg*8;
    const __hip_bfloat16* a1p = (const __hip_bfloat16*)Av + (size_t)(bm + srow + 32)*K + scg*8;
    const float* a0pf = (const float*)Av + (size_t)(bm + srow)*K + scg*8;
    const float* a1pf = (const float*)Av + (size_t)(bm + srow + 32)*K + scg*8;
    const __hip_bfloat16* w0p = W + (size_t)(bn + srow)*K + scg*8;
    const __hip_bfloat16* w1p = W + (size_t)(bn + srow + 32)*K + scg*8;

    for (int k0 = 0; k0 < K; k0 += 64) {
        int4 va0 = {}, va1 = {};
        if (A32) {
            if (v0) {
                float4 p0 = *(const float4*)(a0pf + k0);
                float4 p1 = *(const float4*)(a0pf + k0 + 4);
                va0.x = (int)(f2bf(p0.x) | (f2bf(p0.y) << 16)); va0.y = (int)(f2bf(p0.z) | (f2bf(p0.w) << 16));
                va0.z = (int)(f2bf(p1.x) | (f2bf(p1.y) << 16)); va0.w = (int)(f2bf(p1.z) | (f2bf(p1.w) << 16));
            }
            if (v1) {
                float4 p0 = *(const float4*)(a1pf + k0);
                float4 p1 = *(const float4*)(a1pf + k0 + 4);
                va1.x = (int)(f2bf(p0.x) | (f2bf(p0.y) << 16)); va1.y = (int)(f2bf(p0.z) | (f2bf(p0.w) << 16));
                va1.z = (int)(f2bf(p1.x) | (f2bf(p1.y) << 16)); va1.w = (int)(f2bf(p1.z) | (f2bf(p1.w) << 16));
            }
        } else {
            if (v0) va0 = *(const int4*)(a0p + k0);
            if (v1) va1 = *(const int4*)(a1p + k0);
        }
        int4 vw0 = *(const int4*)(w0p + k0);
        int4 vw1 = *(const int4*)(w1p + k0);
        __syncthreads();
        *(int4*)(As + wo0) = va0;
        *(int4*)(As + wo1) = va1;
        *(int4*)(Ws + wo0) = vw0;
        *(int4*)(Ws + wo1) = vw1;
        __syncthreads();
        #pragma unroll
        for (int ks = 0; ks < 2; ++ks) {
            int kb = ks*64;
            short8 a0 = *(const short8*)(As + ((baseA0 + kb) ^ swz));
            short8 a1 = *(const short8*)(As + ((baseA1 + kb) ^ swz));
            short8 b0 = *(const short8*)(Ws + ((baseB0 + kb) ^ swz));
            short8 b1 = *(const short8*)(Ws + ((baseB1 + kb) ^ swz));
            acc[0][0] = __builtin_amdgcn_mfma_f32_16x16x32_bf16(a0, b0, acc[0][0], 0, 0, 0);
            acc[0][1] = __builtin_amdgcn_mfma_f32_16x16x32_bf16(a0, b1, acc[0][1], 0, 0, 0);
            acc[1][0] = __builtin_amdgcn_mfma_f32_16x16x32_bf16(a1, b0, acc[1][0], 0, 0, 0);
            acc[1][1] = __builtin_amdgcn_mfma_f32_16x16x32_bf16(a1, b1, acc[1][1], 0, 0, 0);
        }
    }
    float bv0 = bias[bn + wn + lrow];
    float bv1 = bias[bn + wn + 16 + lrow];
    #pragma unroll
    for (int mi = 0; mi < 2; ++mi) {
        #pragma unroll
        for (int r = 0; r < 4; ++r) {
            int row = bm + wm + mi*16 + lq*4 + r;
            if (row >= M) continue;
            #pragma unroll
            for (int ni = 0; ni < 2; ++ni) {
                float v = acc[mi][ni][r] + (ni ? bv1 : bv0);
                if (ACT == 1) v = leaky(v);
                int col = bn + wn + ni*16 + lrow;
                if (RES)       Cres[(size_t)row*N + col] += v;
                else if (OUTF) Cres[(size_t)row*N + col] = v;
                else           Cbf[(size_t)row*N + col] = __float2bfloat16(v);
            }
        }
    }
}

// ---------------- depatch gather ----------------
__global__ __launch_bounds__(256) void degather_kernel(const float* __restrict__ G,
    const float* __restrict__ db, float* __restrict__ yimg)
{
    int idx = blockIdx.x*256 + threadIdx.x;
    int b = idx >> 16;
    int pix = idx & 65535;
    int i = pix >> 8, j = pix & 255;
    int fh0 = i >> 1, fw0 = j >> 1;
    size_t r00 = ((size_t)(b*HF + fh0)*WF + fw0)*64;
    size_t r01 = r00 + 64;
    size_t r10 = r00 + (size_t)WF*64;
    size_t r11 = r10 + 64;
    int wr0 = (2 + (i & 1))*4, wr1 = (i & 1)*4;
    int wc0 = 2 + (j & 1), wc1 = (j & 1);
    #pragma unroll
    for (int c = 0; c < 3; ++c) {
        int e = c*16;
        float v = db[c]
                + G[r00 + e + wr0 + wc0] + G[r01 + e + wr0 + wc1]
                + G[r10 + e + wr1 + wc0] + G[r11 + e + wr1 + wc1];
        yimg[((size_t)(b*3 + c) << 16) + pix] = v;
    }
}

// ---------------- residual conv tail ----------------
__global__ __launch_bounds__(256) void res_kernel(const float* __restrict__ y,
    const float* __restrict__ w1, const float* __restrict__ b1,
    const float* __restrict__ w2, const float* __restrict__ b2, float* __restrict__ out)
{
    int idx = blockIdx.x*256 + threadIdx.x;
    int b = idx >> 16;
    int pix = idx & 65535;
    int i = pix >> 8, j = pix & 255;
    float yv[3][5][5];
    #pragma unroll
    for (int c = 0; c < 3; ++c) {
        #pragma unroll
        for (int u = 0; u < 5; ++u) {
            int ii = (i + u - 2 + 256) & 255;
            #pragma unroll
            for (int v = 0; v < 5; ++v) {
                int jj = (j + v - 2 + 256) & 255;
                yv[c][u][v] = y[((size_t)(b*3 + c)*256 + ii)*256 + jj];
            }
        }
    }
    float r1[12];
    #pragma unroll
    for (int rc = 0; rc < 12; ++rc) {
        float a = b1[rc];
        #pragma unroll
        for (int c = 0; c < 3; ++c)
            #pragma unroll
            for (int u = 0; u < 5; ++u)
                #pragma unroll
                for (int v = 0; v < 5; ++v)
                    a += yv[c][u][v] * w1[rc*75 + c*25 + u*5 + v];
        r1[rc] = leaky(a);
    }
    #pragma unroll
    for (int c = 0; c < 3; ++c) {
        float a = b2[c];
        #pragma unroll
        for (int rc = 0; rc < 12; ++rc) a += r1[rc]*w2[c*12 + rc];
        out[((size_t)(b*3 + c)*256 + i)*256 + j] = yv[c][2][2] + a;
    }
}

extern "C" void kernel_launch(void* const* d_in, const int* in_sizes, int n_in,
                              void* d_out, int out_size, void* d_ws, size_t ws_size,
                              hipStream_t stream)
{
    const float* x      = (const float*)d_in[0];
    const float* pos_w  = (const float*)d_in[1];
    const float* pos_b  = (const float*)d_in[2];
    const float* patch_w= (const float*)d_in[3];
    const float* patch_b= (const float*)d_in[4];
    const float* ln1_g  = (const float*)d_in[5];
    const float* ln1_b  = (const float*)d_in[6];
    const float* qkv_w  = (const float*)d_in[7];
    const float* qkv_b  = (const float*)d_in[8];
    const float* rpb    = (const float*)d_in[9];
    const float* proj_w = (const float*)d_in[10];
    const float* proj_b = (const float*)d_in[11];
    const float* ln2_g  = (const float*)d_in[12];
    const float* ln2_b  = (const float*)d_in[13];
    const float* fc1_w  = (const float*)d_in[14];
    const float* fc1_b  = (const float*)d_in[15];
    const float* fc2_w  = (const float*)d_in[16];
    const float* fc2_b  = (const float*)d_in[17];
    const float* dep_w  = (const float*)d_in[18];
    const float* dep_b  = (const float*)d_in[19];
    const float* rc1_w  = (const float*)d_in[20];
    const float* rc1_b  = (const float*)d_in[21];
    const float* rc2_w  = (const float*)d_in[22];
    const float* rc2_b  = (const float*)d_in[23];

    const size_t SZ = (size_t)TOK * 128;
    char* w = (char*)d_ws;
    __hip_bfloat16* f   = (__hip_bfloat16*)w;   w += SZ*2;          // residual stream (bf16)
    __hip_bfloat16* yln = (__hip_bfloat16*)w;   w += SZ*2;          // LN output
    __hip_bfloat16* ao  = (__hip_bfloat16*)w;   w += SZ*2;          // attn output
    __hip_bfloat16* qkvb= (__hip_bfloat16*)w;   w += (size_t)TOK*384*2;
    __hip_bfloat16* hb  = (__hip_bfloat16*)w;   w += (size_t)TOK*512*2;
    float* yimg         = (float*)w;            w += (size_t)BDIM*3*65536*4;
    __hip_bfloat16* wq  = (__hip_bfloat16*)w;   w += (size_t)NQ*2;
    __hip_bfloat16* wp  = (__hip_bfloat16*)w;   w += (size_t)NPJ*2;
    __hip_bfloat16* w1  = (__hip_bfloat16*)w;   w += (size_t)N1*2;
    __hip_bfloat16* w2  = (__hip_bfloat16*)w;   w += (size_t)N2*2;
    __hip_bfloat16* wpat= (__hip_bfloat16*)w;   w += (size_t)NPAT*2;
    __hip_bfloat16* wdep= (__hip_bfloat16*)w;   w += (size_t)NDEP*2;
    float* zero64       = (float*)w;            w += 64*4;

    __hip_bfloat16* icol = qkvb;       // TOK*64 bf16 (disjoint lifetime)
    float* G             = (float*)hb; // TOK*64 f32  (disjoint lifetime)

    const int PREP_TOT = NQ + NPJ + N1 + N2 + NPAT + NDEP + 64;
    prep_weights<<<(PREP_TOT + 255)/256, 256, 0, stream>>>(
        qkv_w, proj_w, fc1_w, fc2_w, patch_w, dep_w, wq, wp, w1, w2, wpat, wdep, zero64);

    im2col_kernel<<<BDIM*HF, 256, 0, stream>>>(x, pos_w, pos_b, icol);

    const int GM = (TOK + 63)/64;       // 521
    const int NTILE = 17*33*BDIM;       // 1122 (8x4 tiles)

    // patchify: f = icol @ wpat^T + b (bf16 residual), fused LN1(l=0) -> yln
    gemmF_kernel<0,0,1,1><<<dim3(GM,1), 256, 0, stream>>>(icol, wpat, patch_b,
        ln1_g, ln1_b, nullptr, f, yln, TOK, 128, 64);

    for (int l = 0; l < 3; ++l) {
        // qkv = yln @ Wq^T + b
        gemmF_kernel<0,0,0,0><<<dim3(GM,3), 256, 0, stream>>>(yln, wq + (size_t)l*384*128,
            qkv_b + l*384, nullptr, nullptr, qkvb, nullptr, nullptr, TOK, 384, 128);
        // MFMA attention (phase-split, 3 blocks/CU)
        attn_mfma_kernel<<<NTILE, 256, 0, stream>>>(qkvb, rpb + l*8*81, ao);
        // f += ao @ Wp^T + b, fused LN2 -> yln
        gemmF_kernel<0,1,0,1><<<dim3(GM,1), 256, 0, stream>>>(ao, wp + (size_t)l*128*128,
            proj_b + l*128, ln2_g + l*128, ln2_b + l*128, nullptr, f, yln, TOK, 128, 128);
        // hb = leaky(yln @ W1^T + b)
        gemmF_kernel<1,0,0,0><<<dim3(GM,4), 256, 0, stream>>>(yln, w1 + (size_t)l*512*128,
            fc1_b + l*512, nullptr, nullptr, hb, nullptr, nullptr, TOK, 512, 128);
        // f += hb @ W2^T + b, fused LN1(l+1) -> yln (skip LN on last layer)
        if (l < 2)
            gemmF_kernel<0,1,0,1><<<dim3(GM,1), 256, 0, stream>>>(hb, w2 + (size_t)l*128*512,
                fc2_b + l*128, ln1_g + (l+1)*128, ln1_b + (l+1)*128, nullptr, f, yln, TOK, 128, 512);
        else
            gemmF_kernel<0,1,0,0><<<dim3(GM,1), 256, 0, stream>>>(hb, w2 + (size_t)l*128*512,
                fc2_b + l*128, nullptr, nullptr, nullptr, f, nullptr, TOK, 128, 512);
    }

    // depatchify: G[T,64] = f[T,128](bf16) @ wdep[64,128]^T
    mgemm_kernel<0,0,1,0><<<dim3(GM,1), 256, 0, stream>>>(f, wdep, zero64,
        nullptr, G, TOK, 64, 128);
    degather_kernel<<<512, 256, 0, stream>>>(G, dep_b, yimg);

    res_kernel<<<512, 256, 0, stream>>>(yimg, rc1_w, rc1_b, rc2_w, rc2_b, (float*)d_out);
}

// Round 19
// 318.778 us; speedup vs baseline: 1.0213x; 1.0213x over previous
//
#include <hip/hip_runtime.h>
#include <hip/hip_bf16.h>
#include <math.h>

#define HF 129
#define WF 129
#define BDIM 2
#define TOK (BDIM*HF*WF)   /* 33282 */
#define DMOD 128
#define VTP 104            /* Vt / P pitch in bf16 elems (208 B, 16B-aligned, bank-spread) */

typedef __attribute__((ext_vector_type(8))) short short8;
typedef __attribute__((ext_vector_type(8))) unsigned short ushort8;
typedef __attribute__((ext_vector_type(4))) float f32x4;

__device__ __forceinline__ float leaky(float v){ return v > 0.f ? v : 0.01f*v; }
__device__ __forceinline__ float bf2f(unsigned short u){ return __uint_as_float(((unsigned int)u) << 16); }
__device__ __forceinline__ unsigned int f2bf(float f){
    unsigned int u = __float_as_uint(f);
    return (u + 0x7fff + ((u >> 16) & 1)) >> 16;
}

// ---------------- one-shot weight prep ----------------
#define NQ 147456
#define NPJ 49152
#define N1 196608
#define N2 196608
#define NPAT 8192
#define NDEP 8192
__global__ __launch_bounds__(256) void prep_weights(
    const float* __restrict__ qkv_w, const float* __restrict__ proj_w,
    const float* __restrict__ fc1_w, const float* __restrict__ fc2_w,
    const float* __restrict__ patch_w, const float* __restrict__ dep_w,
    __hip_bfloat16* __restrict__ wq, __hip_bfloat16* __restrict__ wp,
    __hip_bfloat16* __restrict__ w1, __hip_bfloat16* __restrict__ w2,
    __hip_bfloat16* __restrict__ wpat, __hip_bfloat16* __restrict__ wdep,
    float* __restrict__ zero64)
{
    int off = blockIdx.x*256 + threadIdx.x;
    if (off < NQ) { wq[off] = __float2bfloat16(qkv_w[off]); return; } off -= NQ;
    if (off < NPJ){ wp[off] = __float2bfloat16(proj_w[off]); return; } off -= NPJ;
    if (off < N1) { w1[off] = __float2bfloat16(fc1_w[off]); return; } off -= N1;
    if (off < N2) { w2[off] = __float2bfloat16(fc2_w[off]); return; } off -= N2;
    if (off < NPAT){ int r = off>>6, e = off&63;
        wpat[off] = __float2bfloat16(e < 48 ? patch_w[r*48 + e] : 0.f); return; } off -= NPAT;
    if (off < NDEP){ int e = off>>7, d = off&127;
        wdep[off] = __float2bfloat16(e < 48 ? dep_w[d*48 + e] : 0.f); return; } off -= NDEP;
    if (off < 64) zero64[off] = 0.f;
}

// ---------------- im2col for patchify ----------------
__global__ __launch_bounds__(256) void im2col_kernel(
    const float* __restrict__ x, const float* __restrict__ pos_w, const float* __restrict__ pos_b,
    __hip_bfloat16* __restrict__ G)
{
    __shared__ float xs[12][260];
    int blk = blockIdx.x;           // b*HF + oh
    int b = blk / HF, oh = blk - b*HF;
    int tid = threadIdx.x;
    #pragma unroll
    for (int it = 0; it < 3; ++it) {
        int p = it*4 + (tid >> 6);
        int c = p >> 2, r = p & 3;
        int h = (oh*2 + r - 2 + 256) & 255;
        int w4 = (tid & 63) * 4;
        float4 xv  = *(const float4*)(x     + ((size_t)(b*3 + c)*256 + h)*256 + w4);
        float4 pwv = *(const float4*)(pos_w + ((size_t)c*256 + h)*256 + w4);
        float4 pbv = *(const float4*)(pos_b + ((size_t)c*256 + h)*256 + w4);
        float4 o; o.x = xv.x*pwv.x + pbv.x; o.y = xv.y*pwv.y + pbv.y;
        o.z = xv.z*pwv.z + pbv.z; o.w = xv.w*pwv.w + pbv.w;
        *(float4*)&xs[p][w4] = o;
    }
    __syncthreads();
    int e = tid & 63, og = tid >> 6;
    int c = e >> 4, k = e & 15, kh = k >> 2, kw = k & 3;
    int p = c*4 + kh;
    unsigned short* Grow = (unsigned short*)G + (size_t)blk*WF*64;
    for (int ow = og; ow < WF; ow += 4) {
        unsigned short v = 0;
        if (e < 48) {
            int col = (ow*2 + kw - 2 + 256) & 255;
            v = (unsigned short)f2bf(xs[p][col]);
        }
        Grow[ow*64 + e] = v;
    }
}

// ---------------- gemmF: BM=64, BN=128, BK=64-chunk MFMA GEMM with optional epilogue LN ----------------
// Residual stream Cf is bf16 (LN stats still computed from f32 register accumulators).
// SWZ=1: 1D grid, bm-major tile order + bijective XCD chunking (m204) so the N/128
// column-tiles sharing an A-panel land on the same XCD's L2.
template<int ACT, int RES, int OUTF, int LNE, int SWZ>
__global__ __launch_bounds__(256) void gemmF_kernel(
    const __hip_bfloat16* __restrict__ A, const __hip_bfloat16* __restrict__ W,
    const float* __restrict__ bias, const float* __restrict__ lng, const float* __restrict__ lnb,
    __hip_bfloat16* __restrict__ Cbf, __hip_bfloat16* __restrict__ Cf,
    __hip_bfloat16* __restrict__ yl, int M, int N, int K)
{
    __shared__ __align__(16) char As[64*128];
    __shared__ __align__(16) char Ws[128*128];
    __shared__ float2 lnred[64][2];
    int tid = threadIdx.x;
    int bm, bn;
    if (SWZ) {
        int nwg = gridDim.x;
        int orig = blockIdx.x;
        int q = nwg >> 3, rrem = nwg & 7;
        int xcd = orig & 7, pos = orig >> 3;
        int wgid = (xcd < rrem ? xcd*(q+1) : rrem*(q+1) + (xcd-rrem)*q) + pos;
        int ny = N >> 7;
        bm = (wgid / ny) * 64;
        bn = (wgid - (wgid / ny)*ny) * 128;
    } else {
        bm = blockIdx.x*64; bn = blockIdx.y*128;
    }
    int lane = tid & 63, wid = tid >> 6;
    int wr = (wid >> 1)*32, wc = (wid & 1)*64;
    int lrow = lane & 15, lq = lane >> 4;
    int srow = tid >> 3, scg = tid & 7;
    int swz = (lrow & 7) << 4;
    int awo0 = ((srow     )*128 + scg*16) ^ ((srow&7)<<4);
    int awo1 = ((srow + 32)*128 + scg*16) ^ ((srow&7)<<4);

    bool v0 = (bm + srow) < M, v1 = (bm + srow + 32) < M;
    const __hip_bfloat16* a0p = A + (size_t)(bm + srow)*K + scg*8;
    const __hip_bfloat16* a1p = A + (size_t)(bm + srow + 32)*K + scg*8;
    const __hip_bfloat16* wp0 = W + (size_t)(bn + srow)*K + scg*8;

    f32x4 acc[2][4] = {};
    for (int k0 = 0; k0 < K; k0 += 64) {
        int4 va0 = {}, va1 = {};
        if (v0) va0 = *(const int4*)(a0p + k0);
        if (v1) va1 = *(const int4*)(a1p + k0);
        int4 vw0 = *(const int4*)(wp0 + k0);
        int4 vw1 = *(const int4*)(wp0 + (size_t)32*K + k0);
        int4 vw2 = *(const int4*)(wp0 + (size_t)64*K + k0);
        int4 vw3 = *(const int4*)(wp0 + (size_t)96*K + k0);
        __syncthreads();
        *(int4*)(As + awo0) = va0;
        *(int4*)(As + awo1) = va1;
        *(int4*)(Ws + awo0) = vw0;
        *(int4*)(Ws + awo1) = vw1;
        *(int4*)(Ws + (((srow+64)*128 + scg*16) ^ ((srow&7)<<4))) = vw2;
        *(int4*)(Ws + (((srow+96)*128 + scg*16) ^ ((srow&7)<<4))) = vw3;
        __syncthreads();
        #pragma unroll
        for (int ks = 0; ks < 2; ++ks) {
            int kb = ks*64;
            short8 af[2], bf[4];
            #pragma unroll
            for (int mi = 0; mi < 2; ++mi)
                af[mi] = *(const short8*)(As + (((wr + mi*16 + lrow)*128 + kb + lq*16) ^ swz));
            #pragma unroll
            for (int ni = 0; ni < 4; ++ni)
                bf[ni] = *(const short8*)(Ws + (((wc + ni*16 + lrow)*128 + kb + lq*16) ^ swz));
            #pragma unroll
            for (int mi = 0; mi < 2; ++mi)
                #pragma unroll
                for (int ni = 0; ni < 4; ++ni)
                    acc[mi][ni] = __builtin_amdgcn_mfma_f32_16x16x32_bf16(af[mi], bf[ni], acc[mi][ni], 0, 0, 0);
        }
    }
    float bcol[4];
    #pragma unroll
    for (int ni = 0; ni < 4; ++ni) bcol[ni] = bias[bn + wc + ni*16 + lrow];
    #pragma unroll
    for (int mi = 0; mi < 2; ++mi) {
        #pragma unroll
        for (int r = 0; r < 4; ++r) {
            int row = bm + wr + mi*16 + lq*4 + r;
            bool vrow = row < M;
            #pragma unroll
            for (int ni = 0; ni < 4; ++ni) {
                float v = acc[mi][ni][r] + bcol[ni];
                if (ACT) v = leaky(v);
                if (RES || OUTF) {
                    int col = wc + ni*16 + lrow;
                    size_t idx = (size_t)row*128 + col;
                    if (RES) {
                        float old = vrow ? bf2f(((const unsigned short*)Cf)[idx]) : 0.f;
                        v += old;
                    }
                    if (vrow) ((unsigned short*)Cf)[idx] = (unsigned short)f2bf(v);
                } else {
                    int col = bn + wc + ni*16 + lrow;
                    if (vrow) Cbf[(size_t)row*N + col] = __float2bfloat16(v);
                }
                acc[mi][ni][r] = v;
            }
        }
    }
    if (LNE) {
        float sa[8], ssa[8];
        #pragma unroll
        for (int mi = 0; mi < 2; ++mi)
            #pragma unroll
            for (int r = 0; r < 4; ++r) {
                float s = 0.f, ss = 0.f;
                #pragma unroll
                for (int ni = 0; ni < 4; ++ni) { float v = acc[mi][ni][r]; s += v; ss += v*v; }
                sa[mi*4+r] = s; ssa[mi*4+r] = ss;
            }
        #pragma unroll
        for (int m = 1; m < 16; m <<= 1) {
            #pragma unroll
            for (int i = 0; i < 8; ++i) { sa[i] += __shfl_xor(sa[i], m); ssa[i] += __shfl_xor(ssa[i], m); }
        }
        if (lrow == 0) {
            #pragma unroll
            for (int i = 0; i < 8; ++i)
                lnred[wr + (i>>2)*16 + lq*4 + (i&3)][wc>>6] = make_float2(sa[i], ssa[i]);
        }
        __syncthreads();
        float gcol[4], bbcol[4];
        #pragma unroll
        for (int ni = 0; ni < 4; ++ni) {
            gcol[ni] = lng[wc + ni*16 + lrow];
            bbcol[ni] = lnb[wc + ni*16 + lrow];
        }
        #pragma unroll
        for (int mi = 0; mi < 2; ++mi) {
            #pragma unroll
            for (int r = 0; r < 4; ++r) {
                int rl = wr + mi*16 + lq*4 + r;
                int row = bm + rl;
                if (row >= M) continue;
                float2 h0 = lnred[rl][0], h1 = lnred[rl][1];
                float mean = (h0.x + h1.x) * (1.f/128.f);
                float var = (h0.y + h1.y) * (1.f/128.f) - mean*mean;
                float inv = rsqrtf(var + 1e-5f);
                #pragma unroll
                for (int ni = 0; ni < 4; ++ni) {
                    int col = wc + ni*16 + lrow;
                    float yv = (acc[mi][ni][r] - mean)*inv*gcol[ni] + bbcol[ni];
                    yl[(size_t)row*128 + col] = __float2bfloat16(yv);
                }
            }
        }
    }
}

// ---------------- MFMA neighborhood attention, phase-split K/V (3 blocks/CU) ----------------
__global__ __launch_bounds__(256) void attn_mfma_kernel(
    const __hip_bfloat16* __restrict__ qkv, const float* __restrict__ rpb,
    __hip_bfloat16* __restrict__ o)
{
    __shared__ __align__(16) char KV[26624];           // K (phase A) -> Vt (phase B)
    __shared__ __align__(16) char Pl[4][32*VTP*2];     // per-wave P; base doubles as rpbl in phase A
    float* rpbl = (float*)Pl;
    int blk = blockIdx.x;           // b*(17*33) + tyi*33 + txi
    int b = blk / (17*33);
    int rem = blk - b*(17*33);
    int tyi = rem / 33, txi = rem - tyi*33;
    int y0 = tyi*8, x0 = txi*4;
    int tid = threadIdx.x;
    int lane = tid & 63, wid = tid >> 6;
    int lrow = lane & 15, lq = lane >> 4;

    for (int u = tid; u < 648; u += 256) rpbl[u] = rpb[u];

    // ---- phase A: stage K (c-fast coalesced, swizzled rows) ----
    #pragma unroll
    for (int it = 0; it < 6; ++it) {
        int u = tid + it*256;
        int wtok = u >> 4, c = u & 15;
        int wy = wtok >> 3, wx = wtok & 7;
        int gy = y0 + wy - 2; gy += (gy < 0) ? HF : 0; gy -= (gy >= HF) ? HF : 0;
        int gx = x0 + wx - 2; gx += (gx < 0) ? WF : 0; gx -= (gx >= WF) ? WF : 0;
        size_t tk = (size_t)(b*HF + gy)*WF + gx;
        int4 v = *(const int4*)(qkv + tk*384 + 128 + c*8);
        *(int4*)(KV + wtok*256 + ((c*16) ^ ((wtok & 7) << 4))) = v;
    }
    __syncthreads();

    // ---- phase A: QK^T + bias + exp + rowsum for BOTH heads (scores in regs) ----
    f32x4 sc[2][2][6];
    float inv[2][8];
    int wxv = lrow & 7;
    int wyb = lrow >> 3;
    #pragma unroll
    for (int hh = 0; hh < 2; ++hh) {
        int h = wid + hh*4;
        short8 aq[2];
        #pragma unroll
        for (int mi = 0; mi < 2; ++mi) {
            int q = mi*16 + lrow;
            int ty = q >> 2, tx = q & 3;
            int gy = y0 + ty, gx = x0 + tx;
            int cy = gy < HF ? gy : HF-1, cx = gx < WF ? gx : WF-1;
            size_t tk = (size_t)(b*HF + cy)*WF + cx;
            short8 v = {};
            if (lq < 2) v = *(const short8*)(qkv + tk*384 + h*16 + lq*8);
            aq[mi] = v;
        }
        #pragma unroll
        for (int ni = 0; ni < 6; ++ni) {
            int krow = ni*16 + lrow;
            short8 bk = *(const short8*)(KV + krow*256 + ((h*32 + (lq&1)*16) ^ ((krow&7)<<4)));
            f32x4 zz = {0.f,0.f,0.f,0.f};
            sc[hh][0][ni] = __builtin_amdgcn_mfma_f32_16x16x32_bf16(aq[0], bk, zz, 0, 0, 0);
            sc[hh][1][ni] = __builtin_amdgcn_mfma_f32_16x16x32_bf16(aq[1], bk, zz, 0, 0, 0);
        }
        // bias + mask (clamped f32 rpbl path; C layout: q=mi*16+lq*4+r, w=ni*16+lrow)
        #pragma unroll
        for (int mi = 0; mi < 2; ++mi) {
            int tyq = mi*4 + lq;
            #pragma unroll
            for (int ni = 0; ni < 6; ++ni) {
                int dy = ni*2 + wyb - tyq;
                bool vdy = (dy >= 0) && (dy <= 4);
                int base = (dy + 2)*9 + wxv + 2;
                int cb = base < 3 ? 3 : (base > 80 ? 80 : base);
                const float* bp = rpbl + h*81 + cb - 3;
                float b0 = bp[0], b1 = bp[1], b2 = bp[2], b3 = bp[3];
                float bias_r[4] = {b3, b2, b1, b0};   // bias[r] = rpbl[base - r]
                #pragma unroll
                for (int r = 0; r < 4; ++r) {
                    int dx = wxv - r;
                    bool ok = vdy && (dx >= 0) && (dx <= 4);
                    float s = sc[hh][mi][ni][r]*0.25f + bias_r[r];
                    sc[hh][mi][ni][r] = ok ? s : -1e30f;
                }
            }
        }
        // max-free softmax (logits O(1); masked -> exp(-1e30)=0)
        float sum[8] = {};
        #pragma unroll
        for (int mi = 0; mi < 2; ++mi)
            #pragma unroll
            for (int ni = 0; ni < 6; ++ni)
                #pragma unroll
                for (int r = 0; r < 4; ++r) {
                    float p = __expf(sc[hh][mi][ni][r]);
                    sc[hh][mi][ni][r] = p;
                    sum[mi*4 + r] += p;
                }
        #pragma unroll
        for (int msk = 1; msk < 16; msk <<= 1)
            #pragma unroll
            for (int i = 0; i < 8; ++i) sum[i] += __shfl_xor(sum[i], msk);
        #pragma unroll
        for (int i = 0; i < 8; ++i) inv[hh][i] = 1.f / sum[i];
    }
    __syncthreads();   // all K reads + rpbl reads complete

    // ---- phase B: stage Vt (transposed) into KV ----
    #pragma unroll
    for (int it = 0; it < 6; ++it) {
        int u = tid + it*256;
        int c = u / 96, wtok = u - c*96;
        int wy = wtok >> 3, wx = wtok & 7;
        int gy = y0 + wy - 2; gy += (gy < 0) ? HF : 0; gy -= (gy >= HF) ? HF : 0;
        int gx = x0 + wx - 2; gx += (gx < 0) ? WF : 0; gx -= (gx >= WF) ? WF : 0;
        size_t tk = (size_t)(b*HF + gy)*WF + gx;
        ushort8 v = *(const ushort8*)(qkv + tk*384 + 256 + c*8);
        unsigned short* dst = (unsigned short*)KV + (c*8)*VTP + wtok;
        #pragma unroll
        for (int j = 0; j < 8; ++j) dst[j*VTP] = v[j];
    }
    __syncthreads();   // Vt visible; safe to overwrite Pl (rpbl dead)

    // ---- phase B: per head P write + PV + O write ----
    char* myP = Pl[wid];
    #pragma unroll
    for (int hh = 0; hh < 2; ++hh) {
        int h = wid + hh*4;
        #pragma unroll
        for (int mi = 0; mi < 2; ++mi)
            #pragma unroll
            for (int ni = 0; ni < 6; ++ni)
                #pragma unroll
                for (int r = 0; r < 4; ++r) {
                    int q = mi*16 + lq*4 + r;
                    int w = ni*16 + lrow;
                    ((unsigned short*)myP)[q*VTP + w] =
                        (unsigned short)f2bf(sc[hh][mi][ni][r]);
                }
        f32x4 ov[2] = {};
        #pragma unroll
        for (int kk = 0; kk < 3; ++kk) {
            short8 vb = *(const short8*)(KV + (h*16 + lrow)*(VTP*2) + kk*64 + lq*16);
            #pragma unroll
            for (int mi = 0; mi < 2; ++mi) {
                short8 pa = *(const short8*)(myP + (mi*16 + lrow)*(VTP*2) + kk*64 + lq*16);
                ov[mi] = __builtin_amdgcn_mfma_f32_16x16x32_bf16(pa, vb, ov[mi], 0, 0, 0);
            }
        }
        #pragma unroll
        for (int mi = 0; mi < 2; ++mi) {
            int tyq = mi*4 + lq;
            int gy = y0 + tyq;
            #pragma unroll
            for (int r = 0; r < 4; ++r) {
                int gx = x0 + r;
                if (gy < HF && gx < WF) {
                    size_t tk = (size_t)(b*HF + gy)*WF + gx;
                    ((unsigned short*)o)[tk*128 + h*16 + lrow] =
                        (unsigned short)f2bf(ov[mi][r] * inv[hh][mi*4 + r]);
                }
            }
        }
    }
}

// ---------------- small 64x64 MFMA GEMM (depatch: bf16 f -> f32 G) ----------------
template<int ACT, int RES, int OUTF, int A32>
__global__ __launch_bounds__(256) void mgemm_kernel(
    const void* __restrict__ Av, const __hip_bfloat16* __restrict__ W,
    const float* __restrict__ bias, __hip_bfloat16* __restrict__ Cbf,
    float* __restrict__ Cres, int M, int N, int K)
{
    __shared__ __align__(16) char As[64*128];
    __shared__ __align__(16) char Ws[64*128];
    int tid = threadIdx.x;
    int bm = blockIdx.x*64, bn = blockIdx.y*64;
    int lane = tid & 63, wid = tid >> 6;
    int wm = (wid >> 1)*32, wn = (wid & 1)*32;
    int lrow = lane & 15, lq = lane >> 4;
    int srow = tid >> 3, scg = tid & 7;
    int wo0 = ((srow     )*128 + scg*16) ^ ((srow&7)<<4);
    int wo1 = ((srow + 32)*128 + scg*16) ^ ((srow&7)<<4);
    int swz = (lrow & 7) << 4;
    int baseA0 = (wm + lrow     )*128 + lq*16;
    int baseA1 = (wm + 16 + lrow)*128 + lq*16;
    int baseB0 = (wn + lrow     )*128 + lq*16;
    int baseB1 = (wn + 16 + lrow)*128 + lq*16;

    f32x4 acc[2][2] = {};
    bool v0 = (bm + srow) < M, v1 = (bm + srow + 32) < M;
    const __hip_bfloat16* a0p = (const __hip_bfloat16*)Av + (size_t)(bm + srow)*K + scg*8;
    const __hip_bfloat16* a1p = (const __hip_bfloat16*)Av + (size_t)(bm + srow + 32)*K + scg*8;
    const float* a0pf = (const float*)Av + (size_t)(bm + srow)*K + scg*8;
    const float* a1pf = (const float*)Av + (size_t)(bm + srow + 32)*K + scg*8;
    const __hip_bfloat16* w0p = W + (size_t)(bn + srow)*K + scg*8;
    const __hip_bfloat16* w1p = W + (size_t)(bn + srow + 32)*K + scg*8;

    for (int k0 = 0; k0 < K; k0 += 64) {
        int4 va0 = {}, va1 = {};
        if (A32) {
            if (v0) {
                float4 p0 = *(const float4*)(a0pf + k0);
                float4 p1 = *(const float4*)(a0pf + k0 + 4);
                va0.x = (int)(f2bf(p0.x) | (f2bf(p0.y) << 16)); va0.y = (int)(f2bf(p0.z) | (f2bf(p0.w) << 16));
                va0.z = (int)(f2bf(p1.x) | (f2bf(p1.y) << 16)); va0.w = (int)(f2bf(p1.z) | (f2bf(p1.w) << 16));
            }
            if (v1) {
                float4 p0 = *(const float4*)(a1pf + k0);
                float4 p1 = *(const float4*)(a1pf + k0 + 4);
                va1.x = (int)(f2bf(p0.x) | (f2bf(p0.y) << 16)); va1.y = (int)(f2bf(p0.z) | (f2bf(p0.w) << 16));
                va1.z = (int)(f2bf(p1.x) | (f2bf(p1.y) << 16)); va1.w = (int)(f2bf(p1.z) | (f2bf(p1.w) << 16));
            }
        } else {
            if (v0) va0 = *(const int4*)(a0p + k0);
            if (v1) va1 = *(const int4*)(a1p + k0);
        }
        int4 vw0 = *(const int4*)(w0p + k0);
        int4 vw1 = *(const int4*)(w1p + k0);
        __syncthreads();
        *(int4*)(As + wo0) = va0;
        *(int4*)(As + wo1) = va1;
        *(int4*)(Ws + wo0) = vw0;
        *(int4*)(Ws + wo1) = vw1;
        __syncthreads();
        #pragma unroll
        for (int ks = 0; ks < 2; ++ks) {
            int kb = ks*64;
            short8 a0 = *(const short8*)(As + ((baseA0 + kb) ^ swz));
            short8 a1 = *(const short8*)(As + ((baseA1 + kb) ^ swz));
            short8 b0 = *(const short8*)(Ws + ((baseB0 + kb) ^ swz));
            short8 b1 = *(const short8*)(Ws + ((baseB1 + kb) ^ swz));
            acc[0][0] = __builtin_amdgcn_mfma_f32_16x16x32_bf16(a0, b0, acc[0][0], 0, 0, 0);
            acc[0][1] = __builtin_amdgcn_mfma_f32_16x16x32_bf16(a0, b1, acc[0][1], 0, 0, 0);
            acc[1][0] = __builtin_amdgcn_mfma_f32_16x16x32_bf16(a1, b0, acc[1][0], 0, 0, 0);
            acc[1][1] = __builtin_amdgcn_mfma_f32_16x16x32_bf16(a1, b1, acc[1][1], 0, 0, 0);
        }
    }
    float bv0 = bias[bn + wn + lrow];
    float bv1 = bias[bn + wn + 16 + lrow];
    #pragma unroll
    for (int mi = 0; mi < 2; ++mi) {
        #pragma unroll
        for (int r = 0; r < 4; ++r) {
            int row = bm + wm + mi*16 + lq*4 + r;
            if (row >= M) continue;
            #pragma unroll
            for (int ni = 0; ni < 2; ++ni) {
                float v = acc[mi][ni][r] + (ni ? bv1 : bv0);
                if (ACT == 1) v = leaky(v);
                int col = bn + wn + ni*16 + lrow;
                if (RES)       Cres[(size_t)row*N + col] += v;
                else if (OUTF) Cres[(size_t)row*N + col] = v;
                else           Cbf[(size_t)row*N + col] = __float2bfloat16(v);
            }
        }
    }
}

// ---------------- depatch gather ----------------
__global__ __launch_bounds__(256) void degather_kernel(const float* __restrict__ G,
    const float* __restrict__ db, float* __restrict__ yimg)
{
    int idx = blockIdx.x*256 + threadIdx.x;
    int b = idx >> 16;
    int pix = idx & 65535;
    int i = pix >> 8, j = pix & 255;
    int fh0 = i >> 1, fw0 = j >> 1;
    size_t r00 = ((size_t)(b*HF + fh0)*WF + fw0)*64;
    size_t r01 = r00 + 64;
    size_t r10 = r00 + (size_t)WF*64;
    size_t r11 = r10 + 64;
    int wr0 = (2 + (i & 1))*4, wr1 = (i & 1)*4;
    int wc0 = 2 + (j & 1), wc1 = (j & 1);
    #pragma unroll
    for (int c = 0; c < 3; ++c) {
        int e = c*16;
        float v = db[c]
                + G[r00 + e + wr0 + wc0] + G[r01 + e + wr0 + wc1]
                + G[r10 + e + wr1 + wc0] + G[r11 + e + wr1 + wc1];
        yimg[((size_t)(b*3 + c) << 16) + pix] = v;
    }
}

// ---------------- residual conv tail ----------------
__global__ __launch_bounds__(256) void res_kernel(const float* __restrict__ y,
    const float* __restrict__ w1, const float* __restrict__ b1,
    const float* __restrict__ w2, const float* __restrict__ b2, float* __restrict__ out)
{
    int idx = blockIdx.x*256 + threadIdx.x;
    int b = idx >> 16;
    int pix = idx & 65535;
    int i = pix >> 8, j = pix & 255;
    float yv[3][5][5];
    #pragma unroll
    for (int c = 0; c < 3; ++c) {
        #pragma unroll
        for (int u = 0; u < 5; ++u) {
            int ii = (i + u - 2 + 256) & 255;
            #pragma unroll
            for (int v = 0; v < 5; ++v) {
                int jj = (j + v - 2 + 256) & 255;
                yv[c][u][v] = y[((size_t)(b*3 + c)*256 + ii)*256 + jj];
            }
        }
    }
    float r1[12];
    #pragma unroll
    for (int rc = 0; rc < 12; ++rc) {
        float a = b1[rc];
        #pragma unroll
        for (int c = 0; c < 3; ++c)
            #pragma unroll
            for (int u = 0; u < 5; ++u)
                #pragma unroll
                for (int v = 0; v < 5; ++v)
                    a += yv[c][u][v] * w1[rc*75 + c*25 + u*5 + v];
        r1[rc] = leaky(a);
    }
    #pragma unroll
    for (int c = 0; c < 3; ++c) {
        float a = b2[c];
        #pragma unroll
        for (int rc = 0; rc < 12; ++rc) a += r1[rc]*w2[c*12 + rc];
        out[((size_t)(b*3 + c)*256 + i)*256 + j] = yv[c][2][2] + a;
    }
}

extern "C" void kernel_launch(void* const* d_in, const int* in_sizes, int n_in,
                              void* d_out, int out_size, void* d_ws, size_t ws_size,
                              hipStream_t stream)
{
    const float* x      = (const float*)d_in[0];
    const float* pos_w  = (const float*)d_in[1];
    const float* pos_b  = (const float*)d_in[2];
    const float* patch_w= (const float*)d_in[3];
    const float* patch_b= (const float*)d_in[4];
    const float* ln1_g  = (const float*)d_in[5];
    const float* ln1_b  = (const float*)d_in[6];
    const float* qkv_w  = (const float*)d_in[7];
    const float* qkv_b  = (const float*)d_in[8];
    const float* rpb    = (const float*)d_in[9];
    const float* proj_w = (const float*)d_in[10];
    const float* proj_b = (const float*)d_in[11];
    const float* ln2_g  = (const float*)d_in[12];
    const float* ln2_b  = (const float*)d_in[13];
    const float* fc1_w  = (const float*)d_in[14];
    const float* fc1_b  = (const float*)d_in[15];
    const float* fc2_w  = (const float*)d_in[16];
    const float* fc2_b  = (const float*)d_in[17];
    const float* dep_w  = (const float*)d_in[18];
    const float* dep_b  = (const float*)d_in[19];
    const float* rc1_w  = (const float*)d_in[20];
    const float* rc1_b  = (const float*)d_in[21];
    const float* rc2_w  = (const float*)d_in[22];
    const float* rc2_b  = (const float*)d_in[23];

    const size_t SZ = (size_t)TOK * 128;
    char* w = (char*)d_ws;
    __hip_bfloat16* f   = (__hip_bfloat16*)w;   w += SZ*2;          // residual stream (bf16)
    __hip_bfloat16* yln = (__hip_bfloat16*)w;   w += SZ*2;          // LN output
    __hip_bfloat16* ao  = (__hip_bfloat16*)w;   w += SZ*2;          // attn output
    __hip_bfloat16* qkvb= (__hip_bfloat16*)w;   w += (size_t)TOK*384*2;
    __hip_bfloat16* hb  = (__hip_bfloat16*)w;   w += (size_t)TOK*512*2;
    float* yimg         = (float*)w;            w += (size_t)BDIM*3*65536*4;
    __hip_bfloat16* wq  = (__hip_bfloat16*)w;   w += (size_t)NQ*2;
    __hip_bfloat16* wp  = (__hip_bfloat16*)w;   w += (size_t)NPJ*2;
    __hip_bfloat16* w1  = (__hip_bfloat16*)w;   w += (size_t)N1*2;
    __hip_bfloat16* w2  = (__hip_bfloat16*)w;   w += (size_t)N2*2;
    __hip_bfloat16* wpat= (__hip_bfloat16*)w;   w += (size_t)NPAT*2;
    __hip_bfloat16* wdep= (__hip_bfloat16*)w;   w += (size_t)NDEP*2;
    float* zero64       = (float*)w;            w += 64*4;

    __hip_bfloat16* icol = qkvb;       // TOK*64 bf16 (disjoint lifetime)
    float* G             = (float*)hb; // TOK*64 f32  (disjoint lifetime)

    const int PREP_TOT = NQ + NPJ + N1 + N2 + NPAT + NDEP + 64;
    prep_weights<<<(PREP_TOT + 255)/256, 256, 0, stream>>>(
        qkv_w, proj_w, fc1_w, fc2_w, patch_w, dep_w, wq, wp, w1, w2, wpat, wdep, zero64);

    im2col_kernel<<<BDIM*HF, 256, 0, stream>>>(x, pos_w, pos_b, icol);

    const int GM = (TOK + 63)/64;       // 521
    const int NTILE = 17*33*BDIM;       // 1122 (8x4 tiles)

    // patchify: f = icol @ wpat^T + b (bf16 residual), fused LN1(l=0) -> yln
    gemmF_kernel<0,0,1,1,0><<<dim3(GM,1), 256, 0, stream>>>(icol, wpat, patch_b,
        ln1_g, ln1_b, nullptr, f, yln, TOK, 128, 64);

    for (int l = 0; l < 3; ++l) {
        // qkv = yln @ Wq^T + b  (XCD-swizzled 1D grid: column-tiles share A-panel on same XCD)
        gemmF_kernel<0,0,0,0,1><<<GM*3, 256, 0, stream>>>(yln, wq + (size_t)l*384*128,
            qkv_b + l*384, nullptr, nullptr, qkvb, nullptr, nullptr, TOK, 384, 128);
        // MFMA attention (phase-split, 3 blocks/CU)
        attn_mfma_kernel<<<NTILE, 256, 0, stream>>>(qkvb, rpb + l*8*81, ao);
        // f += ao @ Wp^T + b, fused LN2 -> yln
        gemmF_kernel<0,1,0,1,0><<<dim3(GM,1), 256, 0, stream>>>(ao, wp + (size_t)l*128*128,
            proj_b + l*128, ln2_g + l*128, ln2_b + l*128, nullptr, f, yln, TOK, 128, 128);
        // hb = leaky(yln @ W1^T + b)  (XCD-swizzled)
        gemmF_kernel<1,0,0,0,1><<<GM*4, 256, 0, stream>>>(yln, w1 + (size_t)l*512*128,
            fc1_b + l*512, nullptr, nullptr, hb, nullptr, nullptr, TOK, 512, 128);
        // f += hb @ W2^T + b, fused LN1(l+1) -> yln (skip LN on last layer)
        if (l < 2)
            gemmF_kernel<0,1,0,1,0><<<dim3(GM,1), 256, 0, stream>>>(hb, w2 + (size_t)l*128*512,
                fc2_b + l*128, ln1_g + (l+1)*128, ln1_b + (l+1)*128, nullptr, f, yln, TOK, 128, 512);
        else
            gemmF_kernel<0,1,0,0,0><<<dim3(GM,1), 256, 0, stream>>>(hb, w2 + (size_t)l*128*512,
                fc2_b + l*128, nullptr, nullptr, nullptr, f, nullptr, TOK, 128, 512);
    }

    // depatchify: G[T,64] = f[T,128](bf16) @ wdep[64,128]^T
    mgemm_kernel<0,0,1,0><<<dim3(GM,1), 256, 0, stream>>>(f, wdep, zero64,
        nullptr, G, TOK, 64, 128);
    degather_kernel<<<512, 256, 0, stream>>>(G, dep_b, yimg);

    res_kernel<<<512, 256, 0, stream>>>(yimg, rc1_w, rc1_b, rc2_w, rc2_b, (float*)d_out);
}

// Round 20
// 312.105 us; speedup vs baseline: 1.0431x; 1.0214x over previous
//
#include <hip/hip_runtime.h>
#include <hip/hip_bf16.h>
#include <math.h>

#define HF 129
#define WF 129
#define BDIM 2
#define TOK (BDIM*HF*WF)   /* 33282 */
#define DMOD 128
#define VTP 104            /* Vt / P pitch in bf16 elems (208 B, 16B-aligned, bank-spread) */

typedef __attribute__((ext_vector_type(8))) short short8;
typedef __attribute__((ext_vector_type(8))) unsigned short ushort8;
typedef __attribute__((ext_vector_type(4))) float f32x4;

__device__ __forceinline__ float leaky(float v){ return v > 0.f ? v : 0.01f*v; }
__device__ __forceinline__ float bf2f(unsigned short u){ return __uint_as_float(((unsigned int)u) << 16); }
__device__ __forceinline__ unsigned int f2bf(float f){
    unsigned int u = __float_as_uint(f);
    return (u + 0x7fff + ((u >> 16) & 1)) >> 16;
}

// ---------------- one-shot weight prep ----------------
#define NQ 147456
#define NPJ 49152
#define N1 196608
#define N2 196608
#define NPAT 8192
#define NDEP 8192
__global__ __launch_bounds__(256) void prep_weights(
    const float* __restrict__ qkv_w, const float* __restrict__ proj_w,
    const float* __restrict__ fc1_w, const float* __restrict__ fc2_w,
    const float* __restrict__ patch_w, const float* __restrict__ dep_w,
    __hip_bfloat16* __restrict__ wq, __hip_bfloat16* __restrict__ wp,
    __hip_bfloat16* __restrict__ w1, __hip_bfloat16* __restrict__ w2,
    __hip_bfloat16* __restrict__ wpat, __hip_bfloat16* __restrict__ wdep,
    float* __restrict__ zero64)
{
    int off = blockIdx.x*256 + threadIdx.x;
    if (off < NQ) { wq[off] = __float2bfloat16(qkv_w[off]); return; } off -= NQ;
    if (off < NPJ){ wp[off] = __float2bfloat16(proj_w[off]); return; } off -= NPJ;
    if (off < N1) { w1[off] = __float2bfloat16(fc1_w[off]); return; } off -= N1;
    if (off < N2) { w2[off] = __float2bfloat16(fc2_w[off]); return; } off -= N2;
    if (off < NPAT){ int r = off>>6, e = off&63;
        wpat[off] = __float2bfloat16(e < 48 ? patch_w[r*48 + e] : 0.f); return; } off -= NPAT;
    if (off < NDEP){ int e = off>>7, d = off&127;
        wdep[off] = __float2bfloat16(e < 48 ? dep_w[d*48 + e] : 0.f); return; } off -= NDEP;
    if (off < 64) zero64[off] = 0.f;
}

// ---------------- im2col for patchify ----------------
__global__ __launch_bounds__(256) void im2col_kernel(
    const float* __restrict__ x, const float* __restrict__ pos_w, const float* __restrict__ pos_b,
    __hip_bfloat16* __restrict__ G)
{
    __shared__ float xs[12][260];
    int blk = blockIdx.x;           // b*HF + oh
    int b = blk / HF, oh = blk - b*HF;
    int tid = threadIdx.x;
    #pragma unroll
    for (int it = 0; it < 3; ++it) {
        int p = it*4 + (tid >> 6);
        int c = p >> 2, r = p & 3;
        int h = (oh*2 + r - 2 + 256) & 255;
        int w4 = (tid & 63) * 4;
        float4 xv  = *(const float4*)(x     + ((size_t)(b*3 + c)*256 + h)*256 + w4);
        float4 pwv = *(const float4*)(pos_w + ((size_t)c*256 + h)*256 + w4);
        float4 pbv = *(const float4*)(pos_b + ((size_t)c*256 + h)*256 + w4);
        float4 o; o.x = xv.x*pwv.x + pbv.x; o.y = xv.y*pwv.y + pbv.y;
        o.z = xv.z*pwv.z + pbv.z; o.w = xv.w*pwv.w + pbv.w;
        *(float4*)&xs[p][w4] = o;
    }
    __syncthreads();
    int e = tid & 63, og = tid >> 6;
    int c = e >> 4, k = e & 15, kh = k >> 2, kw = k & 3;
    int p = c*4 + kh;
    unsigned short* Grow = (unsigned short*)G + (size_t)blk*WF*64;
    for (int ow = og; ow < WF; ow += 4) {
        unsigned short v = 0;
        if (e < 48) {
            int col = (ow*2 + kw - 2 + 256) & 255;
            v = (unsigned short)f2bf(xs[p][col]);
        }
        Grow[ow*64 + e] = v;
    }
}

// ---------------- gemmF: BM=64, BN=128, BK=64-chunk MFMA GEMM with optional epilogue LN ----------------
// Residual stream Cf is bf16 (LN stats still computed from f32 register accumulators).
// SWZ=1: 1D grid, bm-major tile order + bijective XCD chunking (m204) so the N/128
// column-tiles sharing an A-panel land on the same XCD's L2.
template<int ACT, int RES, int OUTF, int LNE, int SWZ>
__global__ __launch_bounds__(256) void gemmF_kernel(
    const __hip_bfloat16* __restrict__ A, const __hip_bfloat16* __restrict__ W,
    const float* __restrict__ bias, const float* __restrict__ lng, const float* __restrict__ lnb,
    __hip_bfloat16* __restrict__ Cbf, __hip_bfloat16* __restrict__ Cf,
    __hip_bfloat16* __restrict__ yl, int M, int N, int K)
{
    __shared__ __align__(16) char As[64*128];
    __shared__ __align__(16) char Ws[128*128];
    __shared__ float2 lnred[64][2];
    int tid = threadIdx.x;
    int bm, bn;
    if (SWZ) {
        int nwg = gridDim.x;
        int orig = blockIdx.x;
        int q = nwg >> 3, rrem = nwg & 7;
        int xcd = orig & 7, pos = orig >> 3;
        int wgid = (xcd < rrem ? xcd*(q+1) : rrem*(q+1) + (xcd-rrem)*q) + pos;
        int ny = N >> 7;
        bm = (wgid / ny) * 64;
        bn = (wgid - (wgid / ny)*ny) * 128;
    } else {
        bm = blockIdx.x*64; bn = blockIdx.y*128;
    }
    int lane = tid & 63, wid = tid >> 6;
    int wr = (wid >> 1)*32, wc = (wid & 1)*64;
    int lrow = lane & 15, lq = lane >> 4;
    int srow = tid >> 3, scg = tid & 7;
    int swz = (lrow & 7) << 4;
    int awo0 = ((srow     )*128 + scg*16) ^ ((srow&7)<<4);
    int awo1 = ((srow + 32)*128 + scg*16) ^ ((srow&7)<<4);

    bool v0 = (bm + srow) < M, v1 = (bm + srow + 32) < M;
    const __hip_bfloat16* a0p = A + (size_t)(bm + srow)*K + scg*8;
    const __hip_bfloat16* a1p = A + (size_t)(bm + srow + 32)*K + scg*8;
    const __hip_bfloat16* wp0 = W + (size_t)(bn + srow)*K + scg*8;

    f32x4 acc[2][4] = {};
    for (int k0 = 0; k0 < K; k0 += 64) {
        int4 va0 = {}, va1 = {};
        if (v0) va0 = *(const int4*)(a0p + k0);
        if (v1) va1 = *(const int4*)(a1p + k0);
        int4 vw0 = *(const int4*)(wp0 + k0);
        int4 vw1 = *(const int4*)(wp0 + (size_t)32*K + k0);
        int4 vw2 = *(const int4*)(wp0 + (size_t)64*K + k0);
        int4 vw3 = *(const int4*)(wp0 + (size_t)96*K + k0);
        __syncthreads();
        *(int4*)(As + awo0) = va0;
        *(int4*)(As + awo1) = va1;
        *(int4*)(Ws + awo0) = vw0;
        *(int4*)(Ws + awo1) = vw1;
        *(int4*)(Ws + (((srow+64)*128 + scg*16) ^ ((srow&7)<<4))) = vw2;
        *(int4*)(Ws + (((srow+96)*128 + scg*16) ^ ((srow&7)<<4))) = vw3;
        __syncthreads();
        #pragma unroll
        for (int ks = 0; ks < 2; ++ks) {
            int kb = ks*64;
            short8 af[2], bf[4];
            #pragma unroll
            for (int mi = 0; mi < 2; ++mi)
                af[mi] = *(const short8*)(As + (((wr + mi*16 + lrow)*128 + kb + lq*16) ^ swz));
            #pragma unroll
            for (int ni = 0; ni < 4; ++ni)
                bf[ni] = *(const short8*)(Ws + (((wc + ni*16 + lrow)*128 + kb + lq*16) ^ swz));
            #pragma unroll
            for (int mi = 0; mi < 2; ++mi)
                #pragma unroll
                for (int ni = 0; ni < 4; ++ni)
                    acc[mi][ni] = __builtin_amdgcn_mfma_f32_16x16x32_bf16(af[mi], bf[ni], acc[mi][ni], 0, 0, 0);
        }
    }
    float bcol[4];
    #pragma unroll
    for (int ni = 0; ni < 4; ++ni) bcol[ni] = bias[bn + wc + ni*16 + lrow];
    #pragma unroll
    for (int mi = 0; mi < 2; ++mi) {
        #pragma unroll
        for (int r = 0; r < 4; ++r) {
            int row = bm + wr + mi*16 + lq*4 + r;
            bool vrow = row < M;
            #pragma unroll
            for (int ni = 0; ni < 4; ++ni) {
                float v = acc[mi][ni][r] + bcol[ni];
                if (ACT) v = leaky(v);
                if (RES || OUTF) {
                    int col = wc + ni*16 + lrow;
                    size_t idx = (size_t)row*128 + col;
                    if (RES) {
                        float old = vrow ? bf2f(((const unsigned short*)Cf)[idx]) : 0.f;
                        v += old;
                    }
                    if (vrow) ((unsigned short*)Cf)[idx] = (unsigned short)f2bf(v);
                } else {
                    int col = bn + wc + ni*16 + lrow;
                    if (vrow) Cbf[(size_t)row*N + col] = __float2bfloat16(v);
                }
                acc[mi][ni][r] = v;
            }
        }
    }
    if (LNE) {
        float sa[8], ssa[8];
        #pragma unroll
        for (int mi = 0; mi < 2; ++mi)
            #pragma unroll
            for (int r = 0; r < 4; ++r) {
                float s = 0.f, ss = 0.f;
                #pragma unroll
                for (int ni = 0; ni < 4; ++ni) { float v = acc[mi][ni][r]; s += v; ss += v*v; }
                sa[mi*4+r] = s; ssa[mi*4+r] = ss;
            }
        #pragma unroll
        for (int m = 1; m < 16; m <<= 1) {
            #pragma unroll
            for (int i = 0; i < 8; ++i) { sa[i] += __shfl_xor(sa[i], m); ssa[i] += __shfl_xor(ssa[i], m); }
        }
        if (lrow == 0) {
            #pragma unroll
            for (int i = 0; i < 8; ++i)
                lnred[wr + (i>>2)*16 + lq*4 + (i&3)][wc>>6] = make_float2(sa[i], ssa[i]);
        }
        __syncthreads();
        float gcol[4], bbcol[4];
        #pragma unroll
        for (int ni = 0; ni < 4; ++ni) {
            gcol[ni] = lng[wc + ni*16 + lrow];
            bbcol[ni] = lnb[wc + ni*16 + lrow];
        }
        #pragma unroll
        for (int mi = 0; mi < 2; ++mi) {
            #pragma unroll
            for (int r = 0; r < 4; ++r) {
                int rl = wr + mi*16 + lq*4 + r;
                int row = bm + rl;
                if (row >= M) continue;
                float2 h0 = lnred[rl][0], h1 = lnred[rl][1];
                float mean = (h0.x + h1.x) * (1.f/128.f);
                float var = (h0.y + h1.y) * (1.f/128.f) - mean*mean;
                float inv = rsqrtf(var + 1e-5f);
                #pragma unroll
                for (int ni = 0; ni < 4; ++ni) {
                    int col = wc + ni*16 + lrow;
                    float yv = (acc[mi][ni][r] - mean)*inv*gcol[ni] + bbcol[ni];
                    yl[(size_t)row*128 + col] = __float2bfloat16(yv);
                }
            }
        }
    }
}

// ---------------- MFMA neighborhood attention, phase-split K/V (3 blocks/CU) ----------------
// XCD-chunked blockIdx (bijective m204): adjacent tiles share 50% of the K/V
// window halo; chunked assignment keeps neighbors on the same XCD's L2.
__global__ __launch_bounds__(256) void attn_mfma_kernel(
    const __hip_bfloat16* __restrict__ qkv, const float* __restrict__ rpb,
    __hip_bfloat16* __restrict__ o)
{
    __shared__ __align__(16) char KV[26624];           // K (phase A) -> Vt (phase B)
    __shared__ __align__(16) char Pl[4][32*VTP*2];     // per-wave P; base doubles as rpbl in phase A
    float* rpbl = (float*)Pl;
    int nwg = gridDim.x;
    int orig = blockIdx.x;
    int qch = nwg >> 3, rrem = nwg & 7;
    int xcd = orig & 7, pos = orig >> 3;
    int blk = (xcd < rrem ? xcd*(qch+1) : rrem*(qch+1) + (xcd-rrem)*qch) + pos;
    int b = blk / (17*33);
    int rem = blk - b*(17*33);
    int tyi = rem / 33, txi = rem - tyi*33;
    int y0 = tyi*8, x0 = txi*4;
    int tid = threadIdx.x;
    int lane = tid & 63, wid = tid >> 6;
    int lrow = lane & 15, lq = lane >> 4;

    for (int u = tid; u < 648; u += 256) rpbl[u] = rpb[u];

    // ---- phase A: stage K (c-fast coalesced, swizzled rows) ----
    #pragma unroll
    for (int it = 0; it < 6; ++it) {
        int u = tid + it*256;
        int wtok = u >> 4, c = u & 15;
        int wy = wtok >> 3, wx = wtok & 7;
        int gy = y0 + wy - 2; gy += (gy < 0) ? HF : 0; gy -= (gy >= HF) ? HF : 0;
        int gx = x0 + wx - 2; gx += (gx < 0) ? WF : 0; gx -= (gx >= WF) ? WF : 0;
        size_t tk = (size_t)(b*HF + gy)*WF + gx;
        int4 v = *(const int4*)(qkv + tk*384 + 128 + c*8);
        *(int4*)(KV + wtok*256 + ((c*16) ^ ((wtok & 7) << 4))) = v;
    }
    __syncthreads();

    // ---- phase A: QK^T + bias + exp + rowsum for BOTH heads (scores in regs) ----
    f32x4 sc[2][2][6];
    float inv[2][8];
    int wxv = lrow & 7;
    int wyb = lrow >> 3;
    #pragma unroll
    for (int hh = 0; hh < 2; ++hh) {
        int h = wid + hh*4;
        short8 aq[2];
        #pragma unroll
        for (int mi = 0; mi < 2; ++mi) {
            int q = mi*16 + lrow;
            int ty = q >> 2, tx = q & 3;
            int gy = y0 + ty, gx = x0 + tx;
            int cy = gy < HF ? gy : HF-1, cx = gx < WF ? gx : WF-1;
            size_t tk = (size_t)(b*HF + cy)*WF + cx;
            short8 v = {};
            if (lq < 2) v = *(const short8*)(qkv + tk*384 + h*16 + lq*8);
            aq[mi] = v;
        }
        #pragma unroll
        for (int ni = 0; ni < 6; ++ni) {
            int krow = ni*16 + lrow;
            short8 bk = *(const short8*)(KV + krow*256 + ((h*32 + (lq&1)*16) ^ ((krow&7)<<4)));
            f32x4 zz = {0.f,0.f,0.f,0.f};
            sc[hh][0][ni] = __builtin_amdgcn_mfma_f32_16x16x32_bf16(aq[0], bk, zz, 0, 0, 0);
            sc[hh][1][ni] = __builtin_amdgcn_mfma_f32_16x16x32_bf16(aq[1], bk, zz, 0, 0, 0);
        }
        // bias + mask (clamped f32 rpbl path; C layout: q=mi*16+lq*4+r, w=ni*16+lrow)
        #pragma unroll
        for (int mi = 0; mi < 2; ++mi) {
            int tyq = mi*4 + lq;
            #pragma unroll
            for (int ni = 0; ni < 6; ++ni) {
                int dy = ni*2 + wyb - tyq;
                bool vdy = (dy >= 0) && (dy <= 4);
                int base = (dy + 2)*9 + wxv + 2;
                int cb = base < 3 ? 3 : (base > 80 ? 80 : base);
                const float* bp = rpbl + h*81 + cb - 3;
                float b0 = bp[0], b1 = bp[1], b2 = bp[2], b3 = bp[3];
                float bias_r[4] = {b3, b2, b1, b0};   // bias[r] = rpbl[base - r]
                #pragma unroll
                for (int r = 0; r < 4; ++r) {
                    int dx = wxv - r;
                    bool ok = vdy && (dx >= 0) && (dx <= 4);
                    float s = sc[hh][mi][ni][r]*0.25f + bias_r[r];
                    sc[hh][mi][ni][r] = ok ? s : -1e30f;
                }
            }
        }
        // max-free softmax (logits O(1); masked -> exp(-1e30)=0)
        float sum[8] = {};
        #pragma unroll
        for (int mi = 0; mi < 2; ++mi)
            #pragma unroll
            for (int ni = 0; ni < 6; ++ni)
                #pragma unroll
                for (int r = 0; r < 4; ++r) {
                    float p = __expf(sc[hh][mi][ni][r]);
                    sc[hh][mi][ni][r] = p;
                    sum[mi*4 + r] += p;
                }
        #pragma unroll
        for (int msk = 1; msk < 16; msk <<= 1)
            #pragma unroll
            for (int i = 0; i < 8; ++i) sum[i] += __shfl_xor(sum[i], msk);
        #pragma unroll
        for (int i = 0; i < 8; ++i) inv[hh][i] = 1.f / sum[i];
    }
    __syncthreads();   // all K reads + rpbl reads complete

    // ---- phase B: stage Vt (transposed) into KV ----
    #pragma unroll
    for (int it = 0; it < 6; ++it) {
        int u = tid + it*256;
        int c = u / 96, wtok = u - c*96;
        int wy = wtok >> 3, wx = wtok & 7;
        int gy = y0 + wy - 2; gy += (gy < 0) ? HF : 0; gy -= (gy >= HF) ? HF : 0;
        int gx = x0 + wx - 2; gx += (gx < 0) ? WF : 0; gx -= (gx >= WF) ? WF : 0;
        size_t tk = (size_t)(b*HF + gy)*WF + gx;
        ushort8 v = *(const ushort8*)(qkv + tk*384 + 256 + c*8);
        unsigned short* dst = (unsigned short*)KV + (c*8)*VTP + wtok;
        #pragma unroll
        for (int j = 0; j < 8; ++j) dst[j*VTP] = v[j];
    }
    __syncthreads();   // Vt visible; safe to overwrite Pl (rpbl dead)

    // ---- phase B: per head P write + PV + O write ----
    char* myP = Pl[wid];
    #pragma unroll
    for (int hh = 0; hh < 2; ++hh) {
        int h = wid + hh*4;
        #pragma unroll
        for (int mi = 0; mi < 2; ++mi)
            #pragma unroll
            for (int ni = 0; ni < 6; ++ni)
                #pragma unroll
                for (int r = 0; r < 4; ++r) {
                    int q = mi*16 + lq*4 + r;
                    int w = ni*16 + lrow;
                    ((unsigned short*)myP)[q*VTP + w] =
                        (unsigned short)f2bf(sc[hh][mi][ni][r]);
                }
        f32x4 ov[2] = {};
        #pragma unroll
        for (int kk = 0; kk < 3; ++kk) {
            short8 vb = *(const short8*)(KV + (h*16 + lrow)*(VTP*2) + kk*64 + lq*16);
            #pragma unroll
            for (int mi = 0; mi < 2; ++mi) {
                short8 pa = *(const short8*)(myP + (mi*16 + lrow)*(VTP*2) + kk*64 + lq*16);
                ov[mi] = __builtin_amdgcn_mfma_f32_16x16x32_bf16(pa, vb, ov[mi], 0, 0, 0);
            }
        }
        #pragma unroll
        for (int mi = 0; mi < 2; ++mi) {
            int tyq = mi*4 + lq;
            int gy = y0 + tyq;
            #pragma unroll
            for (int r = 0; r < 4; ++r) {
                int gx = x0 + r;
                if (gy < HF && gx < WF) {
                    size_t tk = (size_t)(b*HF + gy)*WF + gx;
                    ((unsigned short*)o)[tk*128 + h*16 + lrow] =
                        (unsigned short)f2bf(ov[mi][r] * inv[hh][mi*4 + r]);
                }
            }
        }
    }
}

// ---------------- small 64x64 MFMA GEMM (depatch: bf16 f -> f32 G) ----------------
template<int ACT, int RES, int OUTF, int A32>
__global__ __launch_bounds__(256) void mgemm_kernel(
    const void* __restrict__ Av, const __hip_bfloat16* __restrict__ W,
    const float* __restrict__ bias, __hip_bfloat16* __restrict__ Cbf,
    float* __restrict__ Cres, int M, int N, int K)
{
    __shared__ __align__(16) char As[64*128];
    __shared__ __align__(16) char Ws[64*128];
    int tid = threadIdx.x;
    int bm = blockIdx.x*64, bn = blockIdx.y*64;
    int lane = tid & 63, wid = tid >> 6;
    int wm = (wid >> 1)*32, wn = (wid & 1)*32;
    int lrow = lane & 15, lq = lane >> 4;
    int srow = tid >> 3, scg = tid & 7;
    int wo0 = ((srow     )*128 + scg*16) ^ ((srow&7)<<4);
    int wo1 = ((srow + 32)*128 + scg*16) ^ ((srow&7)<<4);
    int swz = (lrow & 7) << 4;
    int baseA0 = (wm + lrow     )*128 + lq*16;
    int baseA1 = (wm + 16 + lrow)*128 + lq*16;
    int baseB0 = (wn + lrow     )*128 + lq*16;
    int baseB1 = (wn + 16 + lrow)*128 + lq*16;

    f32x4 acc[2][2] = {};
    bool v0 = (bm + srow) < M, v1 = (bm + srow + 32) < M;
    const __hip_bfloat16* a0p = (const __hip_bfloat16*)Av + (size_t)(bm + srow)*K + scg*8;
    const __hip_bfloat16* a1p = (const __hip_bfloat16*)Av + (size_t)(bm + srow + 32)*K + scg*8;
    const float* a0pf = (const float*)Av + (size_t)(bm + srow)*K + scg*8;
    const float* a1pf = (const float*)Av + (size_t)(bm + srow + 32)*K + scg*8;
    const __hip_bfloat16* w0p = W + (size_t)(bn + srow)*K + scg*8;
    const __hip_bfloat16* w1p = W + (size_t)(bn + srow + 32)*K + scg*8;

    for (int k0 = 0; k0 < K; k0 += 64) {
        int4 va0 = {}, va1 = {};
        if (A32) {
            if (v0) {
                float4 p0 = *(const float4*)(a0pf + k0);
                float4 p1 = *(const float4*)(a0pf + k0 + 4);
                va0.x = (int)(f2bf(p0.x) | (f2bf(p0.y) << 16)); va0.y = (int)(f2bf(p0.z) | (f2bf(p0.w) << 16));
                va0.z = (int)(f2bf(p1.x) | (f2bf(p1.y) << 16)); va0.w = (int)(f2bf(p1.z) | (f2bf(p1.w) << 16));
            }
            if (v1) {
                float4 p0 = *(const float4*)(a1pf + k0);
                float4 p1 = *(const float4*)(a1pf + k0 + 4);
                va1.x = (int)(f2bf(p0.x) | (f2bf(p0.y) << 16)); va1.y = (int)(f2bf(p0.z) | (f2bf(p0.w) << 16));
                va1.z = (int)(f2bf(p1.x) | (f2bf(p1.y) << 16)); va1.w = (int)(f2bf(p1.z) | (f2bf(p1.w) << 16));
            }
        } else {
            if (v0) va0 = *(const int4*)(a0p + k0);
            if (v1) va1 = *(const int4*)(a1p + k0);
        }
        int4 vw0 = *(const int4*)(w0p + k0);
        int4 vw1 = *(const int4*)(w1p + k0);
        __syncthreads();
        *(int4*)(As + wo0) = va0;
        *(int4*)(As + wo1) = va1;
        *(int4*)(Ws + wo0) = vw0;
        *(int4*)(Ws + wo1) = vw1;
        __syncthreads();
        #pragma unroll
        for (int ks = 0; ks < 2; ++ks) {
            int kb = ks*64;
            short8 a0 = *(const short8*)(As + ((baseA0 + kb) ^ swz));
            short8 a1 = *(const short8*)(As + ((baseA1 + kb) ^ swz));
            short8 b0 = *(const short8*)(Ws + ((baseB0 + kb) ^ swz));
            short8 b1 = *(const short8*)(Ws + ((baseB1 + kb) ^ swz));
            acc[0][0] = __builtin_amdgcn_mfma_f32_16x16x32_bf16(a0, b0, acc[0][0], 0, 0, 0);
            acc[0][1] = __builtin_amdgcn_mfma_f32_16x16x32_bf16(a0, b1, acc[0][1], 0, 0, 0);
            acc[1][0] = __builtin_amdgcn_mfma_f32_16x16x32_bf16(a1, b0, acc[1][0], 0, 0, 0);
            acc[1][1] = __builtin_amdgcn_mfma_f32_16x16x32_bf16(a1, b1, acc[1][1], 0, 0, 0);
        }
    }
    float bv0 = bias[bn + wn + lrow];
    float bv1 = bias[bn + wn + 16 + lrow];
    #pragma unroll
    for (int mi = 0; mi < 2; ++mi) {
        #pragma unroll
        for (int r = 0; r < 4; ++r) {
            int row = bm + wm + mi*16 + lq*4 + r;
            if (row >= M) continue;
            #pragma unroll
            for (int ni = 0; ni < 2; ++ni) {
                float v = acc[mi][ni][r] + (ni ? bv1 : bv0);
                if (ACT == 1) v = leaky(v);
                int col = bn + wn + ni*16 + lrow;
                if (RES)       Cres[(size_t)row*N + col] += v;
                else if (OUTF) Cres[(size_t)row*N + col] = v;
                else           Cbf[(size_t)row*N + col] = __float2bfloat16(v);
            }
        }
    }
}

// ---------------- depatch gather ----------------
__global__ __launch_bounds__(256) void degather_kernel(const float* __restrict__ G,
    const float* __restrict__ db, float* __restrict__ yimg)
{
    int idx = blockIdx.x*256 + threadIdx.x;
    int b = idx >> 16;
    int pix = idx & 65535;
    int i = pix >> 8, j = pix & 255;
    int fh0 = i >> 1, fw0 = j >> 1;
    size_t r00 = ((size_t)(b*HF + fh0)*WF + fw0)*64;
    size_t r01 = r00 + 64;
    size_t r10 = r00 + (size_t)WF*64;
    size_t r11 = r10 + 64;
    int wr0 = (2 + (i & 1))*4, wr1 = (i & 1)*4;
    int wc0 = 2 + (j & 1), wc1 = (j & 1);
    #pragma unroll
    for (int c = 0; c < 3; ++c) {
        int e = c*16;
        float v = db[c]
                + G[r00 + e + wr0 + wc0] + G[r01 + e + wr0 + wc1]
                + G[r10 + e + wr1 + wc0] + G[r11 + e + wr1 + wc1];
        yimg[((size_t)(b*3 + c) << 16) + pix] = v;
    }
}

// ---------------- residual conv tail ----------------
__global__ __launch_bounds__(256) void res_kernel(const float* __restrict__ y,
    const float* __restrict__ w1, const float* __restrict__ b1,
    const float* __restrict__ w2, const float* __restrict__ b2, float* __restrict__ out)
{
    int idx = blockIdx.x*256 + threadIdx.x;
    int b = idx >> 16;
    int pix = idx & 65535;
    int i = pix >> 8, j = pix & 255;
    float yv[3][5][5];
    #pragma unroll
    for (int c = 0; c < 3; ++c) {
        #pragma unroll
        for (int u = 0; u < 5; ++u) {
            int ii = (i + u - 2 + 256) & 255;
            #pragma unroll
            for (int v = 0; v < 5; ++v) {
                int jj = (j + v - 2 + 256) & 255;
                yv[c][u][v] = y[((size_t)(b*3 + c)*256 + ii)*256 + jj];
            }
        }
    }
    float r1[12];
    #pragma unroll
    for (int rc = 0; rc < 12; ++rc) {
        float a = b1[rc];
        #pragma unroll
        for (int c = 0; c < 3; ++c)
            #pragma unroll
            for (int u = 0; u < 5; ++u)
                #pragma unroll
                for (int v = 0; v < 5; ++v)
                    a += yv[c][u][v] * w1[rc*75 + c*25 + u*5 + v];
        r1[rc] = leaky(a);
    }
    #pragma unroll
    for (int c = 0; c < 3; ++c) {
        float a = b2[c];
        #pragma unroll
        for (int rc = 0; rc < 12; ++rc) a += r1[rc]*w2[c*12 + rc];
        out[((size_t)(b*3 + c)*256 + i)*256 + j] = yv[c][2][2] + a;
    }
}

extern "C" void kernel_launch(void* const* d_in, const int* in_sizes, int n_in,
                              void* d_out, int out_size, void* d_ws, size_t ws_size,
                              hipStream_t stream)
{
    const float* x      = (const float*)d_in[0];
    const float* pos_w  = (const float*)d_in[1];
    const float* pos_b  = (const float*)d_in[2];
    const float* patch_w= (const float*)d_in[3];
    const float* patch_b= (const float*)d_in[4];
    const float* ln1_g  = (const float*)d_in[5];
    const float* ln1_b  = (const float*)d_in[6];
    const float* qkv_w  = (const float*)d_in[7];
    const float* qkv_b  = (const float*)d_in[8];
    const float* rpb    = (const float*)d_in[9];
    const float* proj_w = (const float*)d_in[10];
    const float* proj_b = (const float*)d_in[11];
    const float* ln2_g  = (const float*)d_in[12];
    const float* ln2_b  = (const float*)d_in[13];
    const float* fc1_w  = (const float*)d_in[14];
    const float* fc1_b  = (const float*)d_in[15];
    const float* fc2_w  = (const float*)d_in[16];
    const float* fc2_b  = (const float*)d_in[17];
    const float* dep_w  = (const float*)d_in[18];
    const float* dep_b  = (const float*)d_in[19];
    const float* rc1_w  = (const float*)d_in[20];
    const float* rc1_b  = (const float*)d_in[21];
    const float* rc2_w  = (const float*)d_in[22];
    const float* rc2_b  = (const float*)d_in[23];

    const size_t SZ = (size_t)TOK * 128;
    char* w = (char*)d_ws;
    __hip_bfloat16* f   = (__hip_bfloat16*)w;   w += SZ*2;          // residual stream (bf16)
    __hip_bfloat16* yln = (__hip_bfloat16*)w;   w += SZ*2;          // LN output
    __hip_bfloat16* ao  = (__hip_bfloat16*)w;   w += SZ*2;          // attn output
    __hip_bfloat16* qkvb= (__hip_bfloat16*)w;   w += (size_t)TOK*384*2;
    __hip_bfloat16* hb  = (__hip_bfloat16*)w;   w += (size_t)TOK*512*2;
    float* yimg         = (float*)w;            w += (size_t)BDIM*3*65536*4;
    __hip_bfloat16* wq  = (__hip_bfloat16*)w;   w += (size_t)NQ*2;
    __hip_bfloat16* wp  = (__hip_bfloat16*)w;   w += (size_t)NPJ*2;
    __hip_bfloat16* w1  = (__hip_bfloat16*)w;   w += (size_t)N1*2;
    __hip_bfloat16* w2  = (__hip_bfloat16*)w;   w += (size_t)N2*2;
    __hip_bfloat16* wpat= (__hip_bfloat16*)w;   w += (size_t)NPAT*2;
    __hip_bfloat16* wdep= (__hip_bfloat16*)w;   w += (size_t)NDEP*2;
    float* zero64       = (float*)w;            w += 64*4;

    __hip_bfloat16* icol = qkvb;       // TOK*64 bf16 (disjoint lifetime)
    float* G             = (float*)hb; // TOK*64 f32  (disjoint lifetime)

    const int PREP_TOT = NQ + NPJ + N1 + N2 + NPAT + NDEP + 64;
    prep_weights<<<(PREP_TOT + 255)/256, 256, 0, stream>>>(
        qkv_w, proj_w, fc1_w, fc2_w, patch_w, dep_w, wq, wp, w1, w2, wpat, wdep, zero64);

    im2col_kernel<<<BDIM*HF, 256, 0, stream>>>(x, pos_w, pos_b, icol);

    const int GM = (TOK + 63)/64;       // 521
    const int NTILE = 17*33*BDIM;       // 1122 (8x4 tiles)

    // patchify: f = icol @ wpat^T + b (bf16 residual), fused LN1(l=0) -> yln
    gemmF_kernel<0,0,1,1,0><<<dim3(GM,1), 256, 0, stream>>>(icol, wpat, patch_b,
        ln1_g, ln1_b, nullptr, f, yln, TOK, 128, 64);

    for (int l = 0; l < 3; ++l) {
        // qkv = yln @ Wq^T + b  (XCD-swizzled 1D grid)
        gemmF_kernel<0,0,0,0,1><<<GM*3, 256, 0, stream>>>(yln, wq + (size_t)l*384*128,
            qkv_b + l*384, nullptr, nullptr, qkvb, nullptr, nullptr, TOK, 384, 128);
        // MFMA attention (phase-split, XCD-chunked for halo L2 reuse)
        attn_mfma_kernel<<<NTILE, 256, 0, stream>>>(qkvb, rpb + l*8*81, ao);
        // f += ao @ Wp^T + b, fused LN2 -> yln
        gemmF_kernel<0,1,0,1,0><<<dim3(GM,1), 256, 0, stream>>>(ao, wp + (size_t)l*128*128,
            proj_b + l*128, ln2_g + l*128, ln2_b + l*128, nullptr, f, yln, TOK, 128, 128);
        // hb = leaky(yln @ W1^T + b)  (XCD-swizzled)
        gemmF_kernel<1,0,0,0,1><<<GM*4, 256, 0, stream>>>(yln, w1 + (size_t)l*512*128,
            fc1_b + l*512, nullptr, nullptr, hb, nullptr, nullptr, TOK, 512, 128);
        // f += hb @ W2^T + b, fused LN1(l+1) -> yln (skip LN on last layer)
        if (l < 2)
            gemmF_kernel<0,1,0,1,0><<<dim3(GM,1), 256, 0, stream>>>(hb, w2 + (size_t)l*128*512,
                fc2_b + l*128, ln1_g + (l+1)*128, ln1_b + (l+1)*128, nullptr, f, yln, TOK, 128, 512);
        else
            gemmF_kernel<0,1,0,0,0><<<dim3(GM,1), 256, 0, stream>>>(hb, w2 + (size_t)l*128*512,
                fc2_b + l*128, nullptr, nullptr, nullptr, f, nullptr, TOK, 128, 512);
    }

    // depatchify: G[T,64] = f[T,128](bf16) @ wdep[64,128]^T
    mgemm_kernel<0,0,1,0><<<dim3(GM,1), 256, 0, stream>>>(f, wdep, zero64,
        nullptr, G, TOK, 64, 128);
    degather_kernel<<<512, 256, 0, stream>>>(G, dep_b, yimg);

    res_kernel<<<512, 256, 0, stream>>>(yimg, rc1_w, rc1_b, rc2_w, rc2_b, (float*)d_out);
}